// Round 4
// baseline (455.648 us; speedup 1.0000x reference)
//
#include <hip/hip_runtime.h>
#include <float.h>

#define NPTS 8192
#define NB 4
#define NQ 8192
#define KCAP 32

using frag_ab = __attribute__((ext_vector_type(8))) short;   // 8 bf16 (4 VGPRs)
using f32x4   = __attribute__((ext_vector_type(4))) float;

// ---------- monotone float<->uint key for atomic max over floats ----------
__device__ __forceinline__ unsigned fkey(float f) {
  unsigned u = __float_as_uint(f);
  return (u & 0x80000000u) ? ~u : (u | 0x80000000u);
}
__device__ __forceinline__ float funkey(unsigned k) {
  unsigned u = (k & 0x80000000u) ? (k & 0x7fffffffu) : ~k;
  return __uint_as_float(u);
}
__device__ __forceinline__ unsigned short bf16rn(float f) {
  unsigned u = __float_as_uint(f);
  return (unsigned short)((u + 0x7fffu + ((u >> 16) & 1u)) >> 16);
}

// ---------- init: zero gmax keys (4096) + knn hit counters (32768) ----------
__global__ void k_init(unsigned* __restrict__ g, int* __restrict__ cnt) {
  int id = blockIdx.x * 256 + threadIdx.x;
  if (id < 4096) g[id] = 0u;
  if (id < 32768) cnt[id] = 0;
}

// ---------- pack point cloud into float4(x,y,z,pp32) ----------
__global__ __launch_bounds__(256) void k_pack(const float* __restrict__ pc,
                                              float4* __restrict__ pts4) {
  int gq = blockIdx.x * 256 + threadIdx.x;   // b*N + n
  int b = gq >> 13, n = gq & 8191;
  const float* pb = pc + (size_t)b * 3 * NPTS;
  float x = pb[n], y = pb[NPTS + n], z = pb[2 * NPTS + n];
  pts4[gq] = make_float4(x, y, z, fmaf(x, x, fmaf(y, y, z * z)));
}

// ---------- cast G2 weights f32 -> bf16 ----------
__global__ __launch_bounds__(256) void k_castW(const float* __restrict__ W,
                                               unsigned short* __restrict__ Wb) {
  int id = blockIdx.x * 256 + threadIdx.x;
  float4 v = *(const float4*)(W + (size_t)id * 4);
  unsigned short r0 = bf16rn(v.x), r1 = bf16rn(v.y), r2 = bf16rn(v.z), r3 = bf16rn(v.w);
  uint2 pk;
  pk.x = (unsigned)r0 | ((unsigned)r1 << 16);
  pk.y = (unsigned)r2 | ((unsigned)r3 << 16);
  *(uint2*)(Wb + (size_t)id * 4) = pk;
}

// ---------- local encoder: lfT[b][n][128] = relu(W2 relu(W1 p + b1) + b2) ----------
__global__ __launch_bounds__(256) void k_local(const float* __restrict__ pc,
    const float* __restrict__ W1, const float* __restrict__ b1,
    const float* __restrict__ W2, const float* __restrict__ b2,
    float* __restrict__ lfT) {
  __shared__ float sW1[192], sb1[64], sW2[8192], sb2[128];
  int t = threadIdx.x;
  if (t < 192) sW1[t] = W1[t];
  if (t < 64) sb1[t] = b1[t];
  if (t < 128) sb2[t] = b2[t];
  for (int i = t; i < 8192; i += 256) sW2[i] = W2[i];
  __syncthreads();

  int gid = blockIdx.x * 256 + t;
  int b = gid >> 13;
  const float* base = pc + (size_t)b * 3 * NPTS + (gid & 8191);
  float x = base[0], y = base[NPTS], z = base[2 * NPTS];

  float h[64];
#pragma unroll
  for (int j = 0; j < 64; ++j) {
    float v = fmaf(sW1[j * 3 + 2], z, fmaf(sW1[j * 3 + 1], y, fmaf(sW1[j * 3], x, sb1[j])));
    h[j] = fmaxf(v, 0.f);
  }

  float* o = lfT + (size_t)gid * 128;
  for (int c = 0; c < 128; c += 4) {
    float a0 = sb2[c], a1 = sb2[c + 1], a2 = sb2[c + 2], a3 = sb2[c + 3];
#pragma unroll
    for (int j = 0; j < 64; j += 4) {
      float4 w0 = *(const float4*)&sW2[(c + 0) * 64 + j];
      float4 w1 = *(const float4*)&sW2[(c + 1) * 64 + j];
      float4 w2 = *(const float4*)&sW2[(c + 2) * 64 + j];
      float4 w3 = *(const float4*)&sW2[(c + 3) * 64 + j];
      a0 = fmaf(w0.x, h[j], fmaf(w0.y, h[j + 1], fmaf(w0.z, h[j + 2], fmaf(w0.w, h[j + 3], a0))));
      a1 = fmaf(w1.x, h[j], fmaf(w1.y, h[j + 1], fmaf(w1.z, h[j + 2], fmaf(w1.w, h[j + 3], a1))));
      a2 = fmaf(w2.x, h[j], fmaf(w2.y, h[j + 1], fmaf(w2.z, h[j + 2], fmaf(w2.w, h[j + 3], a2))));
      a3 = fmaf(w3.x, h[j], fmaf(w3.y, h[j + 1], fmaf(w3.z, h[j + 2], fmaf(w3.w, h[j + 3], a3))));
    }
    float4 r;
    r.x = fmaxf(a0, 0.f); r.y = fmaxf(a1, 0.f); r.z = fmaxf(a2, 0.f); r.w = fmaxf(a3, 0.f);
    *(float4*)&o[c] = r;
  }
}

// ---------- GEMM1 (f32): g1b16[m][n] = bf16(relu(lfT[m][:] . G1[n][:] + g1b[n])) ----------
__global__ __launch_bounds__(256) void k_gemm1(const float* __restrict__ A,
    const float* __restrict__ Bw, const float* __restrict__ bias,
    unsigned short* __restrict__ C) {
  const int Kdim = 128, Nw = 256;
  __shared__ float As[32][132];
  __shared__ float Bs[32][132];
  int t = threadIdx.x;
  int mBase = blockIdx.x * 128;
  int nBase = blockIdx.y * 128;
  int tx = t & 15, ty = t >> 4;
  float acc[8][8] = {};

  for (int kc = 0; kc < Kdim; kc += 32) {
    __syncthreads();
#pragma unroll
    for (int i = 0; i < 4; ++i) {
      int idx = t + i * 256;
      int r = idx >> 3;
      int k4 = (idx & 7) << 2;
      float4 v = *(const float4*)(A + (size_t)(mBase + r) * Kdim + kc + k4);
      As[k4 + 0][r] = v.x; As[k4 + 1][r] = v.y; As[k4 + 2][r] = v.z; As[k4 + 3][r] = v.w;
      float4 w = *(const float4*)(Bw + (size_t)(nBase + r) * Kdim + kc + k4);
      Bs[k4 + 0][r] = w.x; Bs[k4 + 1][r] = w.y; Bs[k4 + 2][r] = w.z; Bs[k4 + 3][r] = w.w;
    }
    __syncthreads();
#pragma unroll
    for (int kk = 0; kk < 32; ++kk) {
      float a[8], bv[8];
      *(float4*)&a[0] = *(const float4*)&As[kk][ty * 8];
      *(float4*)&a[4] = *(const float4*)&As[kk][ty * 8 + 4];
      *(float4*)&bv[0] = *(const float4*)&Bs[kk][tx * 8];
      *(float4*)&bv[4] = *(const float4*)&Bs[kk][tx * 8 + 4];
#pragma unroll
      for (int i = 0; i < 8; ++i)
#pragma unroll
        for (int j = 0; j < 8; ++j)
          acc[i][j] = fmaf(a[i], bv[j], acc[i][j]);
    }
  }

  float bb[8];
#pragma unroll
  for (int j = 0; j < 8; ++j) bb[j] = bias[nBase + tx * 8 + j];
#pragma unroll
  for (int i = 0; i < 8; ++i) {
    unsigned short* dst = C + (size_t)(mBase + ty * 8 + i) * Nw + nBase + tx * 8;
    uint4 pk;
    unsigned short r[8];
#pragma unroll
    for (int j = 0; j < 8; ++j) r[j] = bf16rn(fmaxf(acc[i][j] + bb[j], 0.f));
    pk.x = (unsigned)r[0] | ((unsigned)r[1] << 16);
    pk.y = (unsigned)r[2] | ((unsigned)r[3] << 16);
    pk.z = (unsigned)r[4] | ((unsigned)r[5] << 16);
    pk.w = (unsigned)r[6] | ((unsigned)r[7] << 16);
    *(uint4*)dst = pk;
  }
}

// ---------- GEMM2 (bf16 MFMA, no C store): column-max -> gmaxK ----------
__global__ __launch_bounds__(256) void k_gmax(const unsigned short* __restrict__ A,
    const unsigned short* __restrict__ W, const float* __restrict__ bias,
    unsigned* __restrict__ gmaxK) {
  __shared__ unsigned smax[128];
  int t = threadIdx.x;
  int w = t >> 6, l = t & 63;
  int lr = l & 15, lg = l >> 4;
  int mBase = blockIdx.x * 128, nBase = blockIdx.y * 128;
  if (t < 128) smax[t] = 0u;
  __syncthreads();

  const unsigned short* arow = A + (size_t)(mBase + w * 32 + lr) * 256 + lg * 8;
  const unsigned short* wrow = W + (size_t)(nBase + lr) * 256 + lg * 8;

  f32x4 acc0[8] = {};
  f32x4 acc1[8] = {};
#pragma unroll
  for (int ko = 0; ko < 256; ko += 32) {
    frag_ab a0 = *(const frag_ab*)(arow + ko);
    frag_ab a1 = *(const frag_ab*)(arow + 16 * 256 + ko);
#pragma unroll
    for (int ni = 0; ni < 8; ++ni) {
      frag_ab bb = *(const frag_ab*)(wrow + (size_t)ni * 16 * 256 + ko);
      acc0[ni] = __builtin_amdgcn_mfma_f32_16x16x32_bf16(a0, bb, acc0[ni], 0, 0, 0);
      acc1[ni] = __builtin_amdgcn_mfma_f32_16x16x32_bf16(a1, bb, acc1[ni], 0, 0, 0);
    }
  }

#pragma unroll
  for (int ni = 0; ni < 8; ++ni) {
    float v = fmaxf(fmaxf(fmaxf(acc0[ni][0], acc0[ni][1]), fmaxf(acc0[ni][2], acc0[ni][3])),
                    fmaxf(fmaxf(acc1[ni][0], acc1[ni][1]), fmaxf(acc1[ni][2], acc1[ni][3])));
    v = fmaxf(v, __shfl_xor(v, 16));
    v = fmaxf(v, __shfl_xor(v, 32));
    if (lg == 0) atomicMax(&smax[ni * 16 + lr], fkey(v));
  }
  __syncthreads();
  if (t < 128) {
    float cm = funkey(smax[t]) + bias[nBase + t];
    atomicMax(&gmaxK[(mBase >> 13) * 1024 + nBase + t], fkey(cm));
  }
}

// ---------- KNN phase A: branchless f32 top-3 DISTANCES per (query, 1024-chunk) ----------
// e-space: d = qq - 2 dot + pp orders identically to e = pp - 2 dot (fixed query).
// Sorted-insert network: k2'=med3(k2,k1,e); k1'=med3(k1,k0,e); k0'=min(k0,e).
#define NET(e)                                                       \
  {                                                                  \
    float nk2 = __builtin_amdgcn_fmed3f(k2, k1, (e));                \
    float nk1 = __builtin_amdgcn_fmed3f(k1, k0, (e));                \
    k0 = fminf(k0, (e));                                             \
    k1 = nk1; k2 = nk2;                                              \
  }

__global__ __launch_bounds__(256) void k_knnA(const float4* __restrict__ pts4,
    const float* __restrict__ qp, float* __restrict__ pA) {
  int gq = blockIdx.x * 256 + threadIdx.x;   // 0..32767
  int b = gq >> 13, qi = gq & 8191;
  int ch = blockIdx.y;                        // 0..7
  const float* qbase = qp + (size_t)b * 3 * NPTS;
  float tax = -2.f * qbase[qi], tay = -2.f * qbase[NPTS + qi], taz = -2.f * qbase[2 * NPTS + qi];

  const float4* P = pts4 + (b << 13) + (ch << 10);
  float k0 = FLT_MAX, k1 = FLT_MAX, k2 = FLT_MAX;
  float4 a0 = P[0], a1 = P[1], a2 = P[2], a3 = P[3];
#pragma unroll 2
  for (int i = 0; i < 1024; i += 4) {
    int nx = (i + 4) & 1023;                  // last prefetch wraps (harmless)
    float4 n0 = P[nx], n1 = P[nx + 1], n2 = P[nx + 2], n3 = P[nx + 3];
    float e0 = fmaf(a0.x, tax, fmaf(a0.y, tay, fmaf(a0.z, taz, a0.w)));
    float e1 = fmaf(a1.x, tax, fmaf(a1.y, tay, fmaf(a1.z, taz, a1.w)));
    float e2 = fmaf(a2.x, tax, fmaf(a2.y, tay, fmaf(a2.z, taz, a2.w)));
    float e3 = fmaf(a3.x, tax, fmaf(a3.y, tay, fmaf(a3.z, taz, a3.w)));
    NET(e0); NET(e1); NET(e2); NET(e3);
    a0 = n0; a1 = n1; a2 = n2; a3 = n3;
  }
  float* pa = pA + (size_t)gq * 24 + ch * 3;
  pa[0] = k0; pa[1] = k1; pa[2] = k2;
}

// ---------- KNN phase B: gated rescan, exact f64 for hits, atomic append ----------
__global__ __launch_bounds__(256) void k_knnB(const float4* __restrict__ pts4,
    const float* __restrict__ qp, const float* __restrict__ pA,
    int* __restrict__ cnt, double* __restrict__ pd2, int* __restrict__ pi2) {
  int gq = blockIdx.x * 256 + threadIdx.x;
  int b = gq >> 13, qi = gq & 8191;
  int ch = blockIdx.y;
  const float* qbase = qp + (size_t)b * 3 * NPTS;
  float qx = qbase[qi], qy = qbase[NPTS + qi], qz = qbase[2 * NPTS + qi];
  float tax = -2.f * qx, tay = -2.f * qy, taz = -2.f * qz;
  double tax64 = -2.0 * (double)qx, tay64 = -2.0 * (double)qy, taz64 = -2.0 * (double)qz;

  // merge 8 chunk-partials -> global 3rd-best tau (exact f32 ordering)
  float k0 = FLT_MAX, k1 = FLT_MAX, k2 = FLT_MAX;
#pragma unroll
  for (int j = 0; j < 24; ++j) { float e = pA[(size_t)gq * 24 + j]; NET(e); }
  // gate: f32 eval error over |e|<=~120 is <~1e-4; 1e-3 slack is 10x margin
  float gate = k2 + 1e-3f;

  const float4* P = pts4 + (b << 13) + (ch << 10);
  int nbase = ch << 10;
  float4 a0 = P[0], a1 = P[1], a2 = P[2], a3 = P[3];
  for (int i = 0; i < 1024; i += 4) {
    int nx = (i + 4) & 1023;
    float4 n0 = P[nx], n1 = P[nx + 1], n2 = P[nx + 2], n3 = P[nx + 3];
    float e0 = fmaf(a0.x, tax, fmaf(a0.y, tay, fmaf(a0.z, taz, a0.w)));
    float e1 = fmaf(a1.x, tax, fmaf(a1.y, tay, fmaf(a1.z, taz, a1.w)));
    float e2 = fmaf(a2.x, tax, fmaf(a2.y, tay, fmaf(a2.z, taz, a2.w)));
    float e3 = fmaf(a3.x, tax, fmaf(a3.y, tay, fmaf(a3.z, taz, a3.w)));
    float mn = fminf(fminf(e0, e1), fminf(e2, e3));
    if (mn <= gate) {
#pragma unroll
      for (int j = 0; j < 4; ++j) {
        float ej = (j == 0) ? e0 : (j == 1) ? e1 : (j == 2) ? e2 : e3;
        float4 cj = (j == 0) ? a0 : (j == 1) ? a1 : (j == 2) ? a2 : a3;
        if (ej <= gate) {
          double cx = (double)cj.x, cy = (double)cj.y, cz = (double)cj.z;
          double pp = fma(cx, cx, fma(cy, cy, cz * cz));
          double e64 = fma(cx, tax64, fma(cy, tay64, fma(cz, taz64, pp)));
          int pos = atomicAdd(&cnt[gq], 1);
          if (pos < KCAP) {
            pd2[(size_t)gq * KCAP + pos] = e64;
            pi2[(size_t)gq * KCAP + pos] = nbase + i + j;
          }
        }
      }
    }
    a0 = n0; a1 = n1; a2 = n2; a3 = n3;
  }
}

// ---------- KNN phase C: exact lexicographic top-3 of appended hits ----------
__global__ __launch_bounds__(256) void k_knnC(const int* __restrict__ cnt,
    const double* __restrict__ pd2, const int* __restrict__ pi2,
    int* __restrict__ ids) {
  int q = blockIdx.x * 256 + threadIdx.x;
  int c = cnt[q]; if (c > KCAP) c = KCAP;
  double d0 = 1e300, d1 = 1e300, d2v = 1e300;
  int i0 = 0x7fffffff, i1 = 0x7fffffff, i2 = 0x7fffffff;
  for (int j = 0; j < c; ++j) {
    double d = pd2[(size_t)q * KCAP + j];
    int n = pi2[(size_t)q * KCAP + j];
    // lexicographic (d, idx): order-invariant under atomic append races
    if (d < d2v || (d == d2v && n < i2)) {
      if (d < d1 || (d == d1 && n < i1)) {
        d2v = d1; i2 = i1;
        if (d < d0 || (d == d0 && n < i0)) { d1 = d0; i1 = i0; d0 = d; i0 = n; }
        else { d1 = d; i1 = n; }
      } else { d2v = d; i2 = n; }
    }
  }
  ids[q * 4 + 0] = i0; ids[q * 4 + 1] = i1; ids[q * 4 + 2] = i2;
}

// ---------- broadcast gmax into out channels [0,1024) ----------
__global__ __launch_bounds__(256) void k_bcast(const unsigned* __restrict__ gmaxK,
                                               float* __restrict__ out) {
  int id = blockIdx.x * 256 + threadIdx.x;   // float4 index
  int m4 = id & 2047;
  int c = (id >> 11) & 1023;
  int b = id >> 21;
  float v = funkey(gmaxK[b * 1024 + c]);
  *(float4*)(out + ((size_t)(b * 1152 + c) << 13) + (m4 << 2)) = make_float4(v, v, v, v);
}

// ---------- gather: out channels [1024,1152) = mean of 3 NN local feats ----------
__global__ __launch_bounds__(256) void k_gather(const float* __restrict__ lfT,
    const int* __restrict__ ids, float* __restrict__ out) {
  int bid = blockIdx.x;
  int b = bid >> 7, mb = bid & 127;
  int t = threadIdx.x;
  int m = mb * 64 + (t & 63);
  int cg = t >> 6;
  int q = b * NQ + m;
  int ia = ids[q * 4 + 0], ib = ids[q * 4 + 1], ic = ids[q * 4 + 2];
  const float* f0 = lfT + ((size_t)b * NPTS + ia) * 128;
  const float* f1 = lfT + ((size_t)b * NPTS + ib) * 128;
  const float* f2 = lfT + ((size_t)b * NPTS + ic) * 128;
  float* ob = out + ((size_t)(b * 1152 + 1024)) * (size_t)NQ + m;
  const float s = 1.f / 3.f;
#pragma unroll
  for (int c4 = 0; c4 < 32; c4 += 4) {
    int c = cg * 32 + c4;
    float4 v0 = *(const float4*)(f0 + c);
    float4 v1 = *(const float4*)(f1 + c);
    float4 v2 = *(const float4*)(f2 + c);
    ob[(size_t)(c + 0) * NQ] = ((v0.x + v1.x) + v2.x) * s;
    ob[(size_t)(c + 1) * NQ] = ((v0.y + v1.y) + v2.y) * s;
    ob[(size_t)(c + 2) * NQ] = ((v0.z + v1.z) + v2.z) * s;
    ob[(size_t)(c + 3) * NQ] = ((v0.w + v1.w) + v2.w) * s;
  }
}

extern "C" void kernel_launch(void* const* d_in, const int* in_sizes, int n_in,
                              void* d_out, int out_size, void* d_ws, size_t ws_size,
                              hipStream_t stream) {
  const float* pc  = (const float*)d_in[0];
  const float* qp  = (const float*)d_in[1];
  const float* W1  = (const float*)d_in[2];
  const float* b1  = (const float*)d_in[3];
  const float* W2  = (const float*)d_in[4];
  const float* b2  = (const float*)d_in[5];
  const float* G1  = (const float*)d_in[6];
  const float* g1b = (const float*)d_in[7];
  const float* G2  = (const float*)d_in[8];
  const float* g2b = (const float*)d_in[9];
  float* out = (float*)d_out;

  char* ws = (char*)d_ws;
  float*          lfT   = (float*)(ws + 0);                 // 16 MB  [B][N][128] f32
  unsigned short* g1b16 = (unsigned short*)(ws + 16777216); // 16 MB  [32768][256] bf16
  unsigned short* G2b16 = (unsigned short*)(ws + 33554432); // 512 KB [1024][256] bf16
  unsigned*       gmaxK = (unsigned*)(ws + 34078720);       // 16 KB  [B][1024]
  float4*         pts4  = (float4*)(ws + 34095104);         // 512 KB [32768] float4
  float*          pA    = (float*)(ws + 34619392);          // 3 MB   [32768][24] f32
  int*            cnt   = (int*)(ws + 37765120);            // 128 KB [32768]
  double*         pd2   = (double*)(ws + 37896192);         // 8 MB   [32768][32] f64
  int*            pi2   = (int*)(ws + 46284800);            // 4 MB   [32768][32]
  int*            ids   = (int*)(ws + 50479104);            // 512 KB [32768][4]

  k_init<<<144, 256, 0, stream>>>(gmaxK, cnt);
  k_pack<<<128, 256, 0, stream>>>(pc, pts4);
  k_castW<<<256, 256, 0, stream>>>(G2, G2b16);
  k_local<<<128, 256, 0, stream>>>(pc, W1, b1, W2, b2, lfT);
  k_gemm1<<<dim3(256, 2), 256, 0, stream>>>(lfT, G1, g1b, g1b16);
  k_gmax<<<dim3(256, 8), 256, 0, stream>>>(g1b16, G2b16, g2b, gmaxK);
  k_knnA<<<dim3(128, 8), 256, 0, stream>>>(pts4, qp, pA);
  k_knnB<<<dim3(128, 8), 256, 0, stream>>>(pts4, qp, pA, cnt, pd2, pi2);
  k_knnC<<<128, 256, 0, stream>>>(cnt, pd2, pi2, ids);
  k_bcast<<<32768, 256, 0, stream>>>(gmaxK, out);
  k_gather<<<512, 256, 0, stream>>>(lfT, ids, out);
}

// Round 5
// 344.761 us; speedup vs baseline: 1.3216x; 1.3216x over previous
//
#include <hip/hip_runtime.h>
#include <float.h>

#define NPTS 8192
#define NB 4
#define NQ 8192

using frag_ab = __attribute__((ext_vector_type(8))) short;   // 8 bf16 (4 VGPRs)
using f32x4   = __attribute__((ext_vector_type(4))) float;

// ---------- monotone float<->uint key for atomic max over floats ----------
__device__ __forceinline__ unsigned fkey(float f) {
  unsigned u = __float_as_uint(f);
  return (u & 0x80000000u) ? ~u : (u | 0x80000000u);
}
__device__ __forceinline__ float funkey(unsigned k) {
  unsigned u = (k & 0x80000000u) ? (k & 0x7fffffffu) : ~k;
  return __uint_as_float(u);
}
__device__ __forceinline__ unsigned short bf16rn(float f) {
  unsigned u = __float_as_uint(f);
  return (unsigned short)((u + 0x7fffu + ((u >> 16) & 1u)) >> 16);
}

// sorted-insert network for top-3 smallest (values only)
#define NET3(e, k0, k1, k2)                                           \
  {                                                                   \
    float nk2 = __builtin_amdgcn_fmed3f(k2, k1, (e));                 \
    float nk1 = __builtin_amdgcn_fmed3f(k1, k0, (e));                 \
    k0 = fminf(k0, (e));                                              \
    k1 = nk1; k2 = nk2;                                               \
  }

// ---------- init gmax keys ----------
__global__ void k_init(unsigned* __restrict__ g) {
  g[blockIdx.x * 256 + threadIdx.x] = 0u;
}

// ---------- pack point cloud into float4(x,y,z,pp32) ----------
__global__ __launch_bounds__(256) void k_pack(const float* __restrict__ pc,
                                              float4* __restrict__ pts4) {
  int gq = blockIdx.x * 256 + threadIdx.x;   // b*N + n
  int b = gq >> 13, n = gq & 8191;
  const float* pb = pc + (size_t)b * 3 * NPTS;
  float x = pb[n], y = pb[NPTS + n], z = pb[2 * NPTS + n];
  pts4[gq] = make_float4(x, y, z, fmaf(x, x, fmaf(y, y, z * z)));
}

// ---------- cast f32 -> bf16 (packed), 4 elems/thread ----------
__global__ __launch_bounds__(256) void k_castW(const float* __restrict__ W,
                                               unsigned short* __restrict__ Wb) {
  int id = blockIdx.x * 256 + threadIdx.x;
  float4 v = *(const float4*)(W + (size_t)id * 4);
  uint2 pk;
  pk.x = (unsigned)bf16rn(v.x) | ((unsigned)bf16rn(v.y) << 16);
  pk.y = (unsigned)bf16rn(v.z) | ((unsigned)bf16rn(v.w) << 16);
  *(uint2*)(Wb + (size_t)id * 4) = pk;
}

// ---------- local encoder: lfT (f32) + lfB (bf16) ----------
__global__ __launch_bounds__(256) void k_local(const float* __restrict__ pc,
    const float* __restrict__ W1, const float* __restrict__ b1,
    const float* __restrict__ W2, const float* __restrict__ b2,
    float* __restrict__ lfT, unsigned short* __restrict__ lfB) {
  __shared__ float sW1[192], sb1[64], sW2[8192], sb2[128];
  int t = threadIdx.x;
  if (t < 192) sW1[t] = W1[t];
  if (t < 64) sb1[t] = b1[t];
  if (t < 128) sb2[t] = b2[t];
  for (int i = t; i < 8192; i += 256) sW2[i] = W2[i];
  __syncthreads();

  int gid = blockIdx.x * 256 + t;
  int b = gid >> 13;
  const float* base = pc + (size_t)b * 3 * NPTS + (gid & 8191);
  float x = base[0], y = base[NPTS], z = base[2 * NPTS];

  float h[64];
#pragma unroll
  for (int j = 0; j < 64; ++j) {
    float v = fmaf(sW1[j * 3 + 2], z, fmaf(sW1[j * 3 + 1], y, fmaf(sW1[j * 3], x, sb1[j])));
    h[j] = fmaxf(v, 0.f);
  }

  float* o = lfT + (size_t)gid * 128;
  unsigned short* ob = lfB + (size_t)gid * 128;
  for (int c = 0; c < 128; c += 4) {
    float a0 = sb2[c], a1 = sb2[c + 1], a2 = sb2[c + 2], a3 = sb2[c + 3];
#pragma unroll
    for (int j = 0; j < 64; j += 4) {
      float4 w0 = *(const float4*)&sW2[(c + 0) * 64 + j];
      float4 w1 = *(const float4*)&sW2[(c + 1) * 64 + j];
      float4 w2 = *(const float4*)&sW2[(c + 2) * 64 + j];
      float4 w3 = *(const float4*)&sW2[(c + 3) * 64 + j];
      a0 = fmaf(w0.x, h[j], fmaf(w0.y, h[j + 1], fmaf(w0.z, h[j + 2], fmaf(w0.w, h[j + 3], a0))));
      a1 = fmaf(w1.x, h[j], fmaf(w1.y, h[j + 1], fmaf(w1.z, h[j + 2], fmaf(w1.w, h[j + 3], a1))));
      a2 = fmaf(w2.x, h[j], fmaf(w2.y, h[j + 1], fmaf(w2.z, h[j + 2], fmaf(w2.w, h[j + 3], a2))));
      a3 = fmaf(w3.x, h[j], fmaf(w3.y, h[j + 1], fmaf(w3.z, h[j + 2], fmaf(w3.w, h[j + 3], a3))));
    }
    float4 r;
    r.x = fmaxf(a0, 0.f); r.y = fmaxf(a1, 0.f); r.z = fmaxf(a2, 0.f); r.w = fmaxf(a3, 0.f);
    *(float4*)&o[c] = r;
    uint2 pk;
    pk.x = (unsigned)bf16rn(r.x) | ((unsigned)bf16rn(r.y) << 16);
    pk.y = (unsigned)bf16rn(r.z) | ((unsigned)bf16rn(r.w) << 16);
    *(uint2*)&ob[c] = pk;
  }
}

// ---------- GEMM1 (bf16 MFMA): g1b16 = bf16(relu(lfB . G1b^T + g1b)) ----------
// A:[32768][128] bf16, W:[256][128] bf16. Tile 128x128, 4 waves x (32 rows x 128 cols).
__global__ __launch_bounds__(256) void k_gemm1(const unsigned short* __restrict__ A,
    const unsigned short* __restrict__ W, const float* __restrict__ bias,
    unsigned short* __restrict__ C) {
  int t = threadIdx.x;
  int w = t >> 6, l = t & 63, lr = l & 15, lg = l >> 4;
  int mBase = blockIdx.x * 128, nBase = blockIdx.y * 128;
  const unsigned short* arow = A + (size_t)(mBase + w * 32 + lr) * 128 + lg * 8;
  const unsigned short* wrow = W + (size_t)(nBase + lr) * 128 + lg * 8;

  f32x4 acc0[8] = {};
  f32x4 acc1[8] = {};
#pragma unroll
  for (int ko = 0; ko < 128; ko += 32) {
    frag_ab a0 = *(const frag_ab*)(arow + ko);
    frag_ab a1 = *(const frag_ab*)(arow + 16 * 128 + ko);
#pragma unroll
    for (int ni = 0; ni < 8; ++ni) {
      frag_ab bb = *(const frag_ab*)(wrow + (size_t)ni * 16 * 128 + ko);
      acc0[ni] = __builtin_amdgcn_mfma_f32_16x16x32_bf16(a0, bb, acc0[ni], 0, 0, 0);
      acc1[ni] = __builtin_amdgcn_mfma_f32_16x16x32_bf16(a1, bb, acc1[ni], 0, 0, 0);
    }
  }
#pragma unroll
  for (int ni = 0; ni < 8; ++ni) {
    int col = nBase + ni * 16 + lr;
    float bb = bias[col];
    int row0 = mBase + w * 32 + lg * 4;
#pragma unroll
    for (int r = 0; r < 4; ++r) {
      C[(size_t)(row0 + r) * 256 + col] = bf16rn(fmaxf(acc0[ni][r] + bb, 0.f));
      C[(size_t)(row0 + 16 + r) * 256 + col] = bf16rn(fmaxf(acc1[ni][r] + bb, 0.f));
    }
  }
}

// ---------- GEMM2 (bf16 MFMA, no C store): column-max -> gmaxK ----------
__global__ __launch_bounds__(256) void k_gmax(const unsigned short* __restrict__ A,
    const unsigned short* __restrict__ W, const float* __restrict__ bias,
    unsigned* __restrict__ gmaxK) {
  __shared__ unsigned smax[128];
  int t = threadIdx.x;
  int w = t >> 6, l = t & 63;
  int lr = l & 15, lg = l >> 4;
  int mBase = blockIdx.x * 128, nBase = blockIdx.y * 128;
  if (t < 128) smax[t] = 0u;
  __syncthreads();

  const unsigned short* arow = A + (size_t)(mBase + w * 32 + lr) * 256 + lg * 8;
  const unsigned short* wrow = W + (size_t)(nBase + lr) * 256 + lg * 8;

  f32x4 acc0[8] = {};
  f32x4 acc1[8] = {};
#pragma unroll
  for (int ko = 0; ko < 256; ko += 32) {
    frag_ab a0 = *(const frag_ab*)(arow + ko);
    frag_ab a1 = *(const frag_ab*)(arow + 16 * 256 + ko);
#pragma unroll
    for (int ni = 0; ni < 8; ++ni) {
      frag_ab bb = *(const frag_ab*)(wrow + (size_t)ni * 16 * 256 + ko);
      acc0[ni] = __builtin_amdgcn_mfma_f32_16x16x32_bf16(a0, bb, acc0[ni], 0, 0, 0);
      acc1[ni] = __builtin_amdgcn_mfma_f32_16x16x32_bf16(a1, bb, acc1[ni], 0, 0, 0);
    }
  }

#pragma unroll
  for (int ni = 0; ni < 8; ++ni) {
    float v = fmaxf(fmaxf(fmaxf(acc0[ni][0], acc0[ni][1]), fmaxf(acc0[ni][2], acc0[ni][3])),
                    fmaxf(fmaxf(acc1[ni][0], acc1[ni][1]), fmaxf(acc1[ni][2], acc1[ni][3])));
    v = fmaxf(v, __shfl_xor(v, 16));
    v = fmaxf(v, __shfl_xor(v, 32));
    if (lg == 0) atomicMax(&smax[ni * 16 + lr], fkey(v));
  }
  __syncthreads();
  if (t < 128) {
    float cm = funkey(smax[t]) + bias[nBase + t];
    atomicMax(&gmaxK[(mBase >> 13) * 1024 + nBase + t], fkey(cm));
  }
}

// ---------- KNN A: 4 queries/thread, branchless f32 top-3 per (query, 512-chunk) ----------
__global__ __launch_bounds__(256) void k_knnA(const float4* __restrict__ pts4,
    const float* __restrict__ qp, float* __restrict__ pA) {
  int gq4 = blockIdx.x * 256 + threadIdx.x;   // 0..8191 (4 queries each)
  int b = blockIdx.x >> 3;                     // block-uniform batch
  int qi0 = (gq4 * 4) & 8191;
  int ch = blockIdx.y;                         // 0..15
  const float* qb = qp + (size_t)b * 3 * NPTS;
  float4 qx = *(const float4*)(qb + qi0);
  float4 qy = *(const float4*)(qb + NPTS + qi0);
  float4 qz = *(const float4*)(qb + 2 * NPTS + qi0);
  float tax[4] = {-2.f * qx.x, -2.f * qx.y, -2.f * qx.z, -2.f * qx.w};
  float tay[4] = {-2.f * qy.x, -2.f * qy.y, -2.f * qy.z, -2.f * qy.w};
  float taz[4] = {-2.f * qz.x, -2.f * qz.y, -2.f * qz.z, -2.f * qz.w};

  const float4* P = pts4 + (b << 13) + (ch << 9);
  float k0[4], k1[4], k2[4];
#pragma unroll
  for (int j = 0; j < 4; ++j) { k0[j] = FLT_MAX; k1[j] = FLT_MAX; k2[j] = FLT_MAX; }

  float4 a0 = P[0], a1 = P[1], a2 = P[2], a3 = P[3];
  for (int i = 0; i < 512; i += 4) {
    int nx = (i + 4) & 511;
    float4 n0 = P[nx], n1 = P[nx + 1], n2 = P[nx + 2], n3 = P[nx + 3];
#pragma unroll
    for (int c = 0; c < 4; ++c) {
      float4 p = (c == 0) ? a0 : (c == 1) ? a1 : (c == 2) ? a2 : a3;
#pragma unroll
      for (int j = 0; j < 4; ++j) {
        float e = fmaf(p.x, tax[j], fmaf(p.y, tay[j], fmaf(p.z, taz[j], p.w)));
        NET3(e, k0[j], k1[j], k2[j]);
      }
    }
    a0 = n0; a1 = n1; a2 = n2; a3 = n3;
  }
  float* pa = pA + ((size_t)gq4 * 16 + ch) * 12;
#pragma unroll
  for (int j = 0; j < 4; ++j) {
    pa[j * 3 + 0] = k0[j]; pa[j * 3 + 1] = k1[j]; pa[j * 3 + 2] = k2[j];
  }
}

// ---------- KNN gate: merge 16 chunk-partials -> tau + slack per query ----------
__global__ __launch_bounds__(256) void k_gate(const float* __restrict__ pA,
                                              float* __restrict__ gate) {
  int gq4 = blockIdx.x * 256 + threadIdx.x;   // 0..8191
  const float* pa = pA + (size_t)gq4 * 192;
  float g[4];
#pragma unroll
  for (int j = 0; j < 4; ++j) {
    float k0 = FLT_MAX, k1 = FLT_MAX, k2 = FLT_MAX;
    for (int ch = 0; ch < 16; ++ch) {
      float e0 = pa[ch * 12 + j * 3 + 0];
      float e1 = pa[ch * 12 + j * 3 + 1];
      float e2 = pa[ch * 12 + j * 3 + 2];
      NET3(e0, k0, k1, k2); NET3(e1, k0, k1, k2); NET3(e2, k0, k1, k2);
    }
    g[j] = k2 + 1e-3f;   // f32 eval band ~3e-5; 30x margin
  }
  *(float4*)(gate + (size_t)gq4 * 4) = make_float4(g[0], g[1], g[2], g[3]);
}

// ---------- KNN B: gated rescan; exact f64 top-3 per (query, chunk), no atomics ----------
__global__ __launch_bounds__(256) void k_knnB(const float4* __restrict__ pts4,
    const float* __restrict__ qp, const float* __restrict__ gate,
    double* __restrict__ pd2, int* __restrict__ pi2) {
  int gq4 = blockIdx.x * 256 + threadIdx.x;
  int b = blockIdx.x >> 3;
  int qi0 = (gq4 * 4) & 8191;
  int ch = blockIdx.y;
  const float* qb = qp + (size_t)b * 3 * NPTS;
  float4 qx = *(const float4*)(qb + qi0);
  float4 qy = *(const float4*)(qb + NPTS + qi0);
  float4 qz = *(const float4*)(qb + 2 * NPTS + qi0);
  float tax[4] = {-2.f * qx.x, -2.f * qx.y, -2.f * qx.z, -2.f * qx.w};
  float tay[4] = {-2.f * qy.x, -2.f * qy.y, -2.f * qy.z, -2.f * qy.w};
  float taz[4] = {-2.f * qz.x, -2.f * qz.y, -2.f * qz.z, -2.f * qz.w};
  float qxs[4] = {qx.x, qx.y, qx.z, qx.w};
  float qys[4] = {qy.x, qy.y, qy.z, qy.w};
  float qzs[4] = {qz.x, qz.y, qz.z, qz.w};
  float4 g4 = *(const float4*)(gate + (size_t)gq4 * 4);
  float gt[4] = {g4.x, g4.y, g4.z, g4.w};

  double d0[4], d1[4], d2[4];
  int i0[4], i1[4], i2[4];
#pragma unroll
  for (int j = 0; j < 4; ++j) {
    d0[j] = 1e300; d1[j] = 1e300; d2[j] = 1e300;
    i0[j] = 0; i1[j] = 0; i2[j] = 0;
  }

  const float4* P = pts4 + (b << 13) + (ch << 9);
  int nb = ch << 9;
  float4 a0 = P[0], a1 = P[1], a2 = P[2], a3 = P[3];
  for (int i = 0; i < 512; i += 4) {
    int nx = (i + 4) & 511;
    float4 n0 = P[nx], n1 = P[nx + 1], n2 = P[nx + 2], n3 = P[nx + 3];
#pragma unroll
    for (int j = 0; j < 4; ++j) {
      float e0 = fmaf(a0.x, tax[j], fmaf(a0.y, tay[j], fmaf(a0.z, taz[j], a0.w)));
      float e1 = fmaf(a1.x, tax[j], fmaf(a1.y, tay[j], fmaf(a1.z, taz[j], a1.w)));
      float e2 = fmaf(a2.x, tax[j], fmaf(a2.y, tay[j], fmaf(a2.z, taz[j], a2.w)));
      float e3 = fmaf(a3.x, tax[j], fmaf(a3.y, tay[j], fmaf(a3.z, taz[j], a3.w)));
      float mn = fminf(fminf(e0, e1), fminf(e2, e3));
      if (mn <= gt[j]) {                      // rare (~9% of wave-groups)
        double tax64 = -2.0 * (double)qxs[j];
        double tay64 = -2.0 * (double)qys[j];
        double taz64 = -2.0 * (double)qzs[j];
#pragma unroll
        for (int c = 0; c < 4; ++c) {
          float ec = (c == 0) ? e0 : (c == 1) ? e1 : (c == 2) ? e2 : e3;
          float4 p = (c == 0) ? a0 : (c == 1) ? a1 : (c == 2) ? a2 : a3;
          if (ec <= gt[j]) {
            double cx = (double)p.x, cy = (double)p.y, cz = (double)p.z;
            double pp = fma(cx, cx, fma(cy, cy, cz * cz));
            double e64 = fma(cx, tax64, fma(cy, tay64, fma(cz, taz64, pp)));
            int n = nb + i + c;
            if (e64 < d2[j]) {                // strict <: scan order = index order
              if (e64 < d1[j]) {
                d2[j] = d1[j]; i2[j] = i1[j];
                if (e64 < d0[j]) { d1[j] = d0[j]; i1[j] = i0[j]; d0[j] = e64; i0[j] = n; }
                else { d1[j] = e64; i1[j] = n; }
              } else { d2[j] = e64; i2[j] = n; }
            }
          }
        }
      }
    }
    a0 = n0; a1 = n1; a2 = n2; a3 = n3;
  }

  double* pdq = pd2 + ((size_t)gq4 * 16 + ch) * 12;
  int* piq = pi2 + ((size_t)gq4 * 16 + ch) * 12;
#pragma unroll
  for (int j = 0; j < 4; ++j) {
    pdq[j * 3 + 0] = d0[j]; pdq[j * 3 + 1] = d1[j]; pdq[j * 3 + 2] = d2[j];
    piq[j * 3 + 0] = i0[j]; piq[j * 3 + 1] = i1[j]; piq[j * 3 + 2] = i2[j];
  }
}

// ---------- KNN C: merge 16 chunk-partials (chunk order = index order, strict <) ----------
__global__ __launch_bounds__(256) void k_knnC(const double* __restrict__ pd2,
    const int* __restrict__ pi2, int* __restrict__ ids) {
  int q = blockIdx.x * 256 + threadIdx.x;
  int gq4 = q >> 2, j = q & 3;
  double d0 = 1e300, d1 = 1e300, d2v = 1e300;
  int i0 = 0, i1 = 0, i2 = 0;
  for (int ch = 0; ch < 16; ++ch) {
    const double* pdq = pd2 + ((size_t)gq4 * 16 + ch) * 12 + j * 3;
    const int* piq = pi2 + ((size_t)gq4 * 16 + ch) * 12 + j * 3;
#pragma unroll
    for (int k = 0; k < 3; ++k) {
      double d = pdq[k];
      int n = piq[k];
      if (d < d2v) {
        if (d < d1) {
          d2v = d1; i2 = i1;
          if (d < d0) { d1 = d0; i1 = i0; d0 = d; i0 = n; }
          else { d1 = d; i1 = n; }
        } else { d2v = d; i2 = n; }
      }
    }
  }
  ids[q * 4 + 0] = i0; ids[q * 4 + 1] = i1; ids[q * 4 + 2] = i2;
}

// ---------- broadcast gmax into out channels [0,1024) ----------
__global__ __launch_bounds__(256) void k_bcast(const unsigned* __restrict__ gmaxK,
                                               float* __restrict__ out) {
  int id = blockIdx.x * 256 + threadIdx.x;   // float4 index
  int m4 = id & 2047;
  int c = (id >> 11) & 1023;
  int b = id >> 21;
  float v = funkey(gmaxK[b * 1024 + c]);
  *(float4*)(out + ((size_t)(b * 1152 + c) << 13) + (m4 << 2)) = make_float4(v, v, v, v);
}

// ---------- gather: out channels [1024,1152) = mean of 3 NN local feats ----------
__global__ __launch_bounds__(256) void k_gather(const float* __restrict__ lfT,
    const int* __restrict__ ids, float* __restrict__ out) {
  int bid = blockIdx.x;
  int b = bid >> 7, mb = bid & 127;
  int t = threadIdx.x;
  int m = mb * 64 + (t & 63);
  int cg = t >> 6;
  int q = b * NQ + m;
  int ia = ids[q * 4 + 0], ib = ids[q * 4 + 1], ic = ids[q * 4 + 2];
  const float* f0 = lfT + ((size_t)b * NPTS + ia) * 128;
  const float* f1 = lfT + ((size_t)b * NPTS + ib) * 128;
  const float* f2 = lfT + ((size_t)b * NPTS + ic) * 128;
  float* ob = out + ((size_t)(b * 1152 + 1024)) * (size_t)NQ + m;
  const float s = 1.f / 3.f;
#pragma unroll
  for (int c4 = 0; c4 < 32; c4 += 4) {
    int c = cg * 32 + c4;
    float4 v0 = *(const float4*)(f0 + c);
    float4 v1 = *(const float4*)(f1 + c);
    float4 v2 = *(const float4*)(f2 + c);
    ob[(size_t)(c + 0) * NQ] = ((v0.x + v1.x) + v2.x) * s;
    ob[(size_t)(c + 1) * NQ] = ((v0.y + v1.y) + v2.y) * s;
    ob[(size_t)(c + 2) * NQ] = ((v0.z + v1.z) + v2.z) * s;
    ob[(size_t)(c + 3) * NQ] = ((v0.w + v1.w) + v2.w) * s;
  }
}

extern "C" void kernel_launch(void* const* d_in, const int* in_sizes, int n_in,
                              void* d_out, int out_size, void* d_ws, size_t ws_size,
                              hipStream_t stream) {
  const float* pc  = (const float*)d_in[0];
  const float* qp  = (const float*)d_in[1];
  const float* W1  = (const float*)d_in[2];
  const float* b1  = (const float*)d_in[3];
  const float* W2  = (const float*)d_in[4];
  const float* b2  = (const float*)d_in[5];
  const float* G1  = (const float*)d_in[6];
  const float* g1b = (const float*)d_in[7];
  const float* G2  = (const float*)d_in[8];
  const float* g2b = (const float*)d_in[9];
  float* out = (float*)d_out;

  char* ws = (char*)d_ws;
  // persistent:
  float*          lfT   = (float*)(ws + 0);                  // 16 MB [B][N][128] f32
  int*            ids   = (int*)(ws + 42074112);             // 512 KB
  float4*         pts4  = (float4*)(ws + 42598400);          // 512 KB
  unsigned short* G1b16 = (unsigned short*)(ws + 43122688);  // 64 KB
  unsigned short* G2b16 = (unsigned short*)(ws + 43188224);  // 512 KB
  unsigned*       gmaxK = (unsigned*)(ws + 43712512);        // 16 KB
  // KNN scratch (dead after k_knnC):
  float*          pA    = (float*)(ws + 16777216);           // 6.3 MB [8192][16][12]
  double*         pd2   = (double*)(ws + 23068672);          // 12.6 MB [8192][16][12] f64
  int*            pi2   = (int*)(ws + 35651584);             // 6.3 MB
  float*          gate  = (float*)(ws + 41943040);           // 128 KB [32768]
  // encoder tensors (alias knn scratch; written after knn done):
  unsigned short* lfB   = (unsigned short*)(ws + 16777216);  // 8 MB [32768][128] bf16
  unsigned short* g1b16 = (unsigned short*)(ws + 25165824);  // 16 MB [32768][256] bf16

  // KNN first (scratch region is reused by encoder afterwards; stream-ordered)
  k_pack<<<128, 256, 0, stream>>>(pc, pts4);
  k_knnA<<<dim3(32, 16), 256, 0, stream>>>(pts4, qp, pA);
  k_gate<<<32, 256, 0, stream>>>(pA, gate);
  k_knnB<<<dim3(32, 16), 256, 0, stream>>>(pts4, qp, gate, pd2, pi2);
  k_knnC<<<128, 256, 0, stream>>>(pd2, pi2, ids);
  // encoder
  k_init<<<16, 256, 0, stream>>>(gmaxK);
  k_castW<<<32, 256, 0, stream>>>(G1, G1b16);
  k_castW<<<256, 256, 0, stream>>>(G2, G2b16);
  k_local<<<128, 256, 0, stream>>>(pc, W1, b1, W2, b2, lfT, lfB);
  k_gemm1<<<dim3(256, 2), 256, 0, stream>>>(lfB, G1b16, g1b, g1b16);
  k_gmax<<<dim3(256, 8), 256, 0, stream>>>(g1b16, G2b16, g2b, gmaxK);
  // outputs
  k_bcast<<<32768, 256, 0, stream>>>(gmaxK, out);
  k_gather<<<512, 256, 0, stream>>>(lfT, ids, out);
}

// Round 6
// 331.205 us; speedup vs baseline: 1.3757x; 1.0409x over previous
//
#include <hip/hip_runtime.h>
#include <float.h>

#define NPTS 8192
#define NB 4
#define NQ 8192

using frag_ab = __attribute__((ext_vector_type(8))) short;   // 8 bf16 (4 VGPRs)
using f32x4   = __attribute__((ext_vector_type(4))) float;

// ---------- monotone float<->uint key for atomic max over floats ----------
__device__ __forceinline__ unsigned fkey(float f) {
  unsigned u = __float_as_uint(f);
  return (u & 0x80000000u) ? ~u : (u | 0x80000000u);
}
__device__ __forceinline__ float funkey(unsigned k) {
  unsigned u = (k & 0x80000000u) ? (k & 0x7fffffffu) : ~k;
  return __uint_as_float(u);
}
__device__ __forceinline__ unsigned short bf16rn(float f) {
  unsigned u = __float_as_uint(f);
  return (unsigned short)((u + 0x7fffu + ((u >> 16) & 1u)) >> 16);
}

// sorted-insert network for top-3 smallest (values only)
#define NET3(e, k0, k1, k2)                                           \
  {                                                                   \
    float nk2 = __builtin_amdgcn_fmed3f(k2, k1, (e));                 \
    float nk1 = __builtin_amdgcn_fmed3f(k1, k0, (e));                 \
    k0 = fminf(k0, (e));                                              \
    k1 = nk1; k2 = nk2;                                               \
  }

// ---------- prep: pack pts4 + cast G1/G2 -> bf16 + init gmax keys ----------
__global__ __launch_bounds__(256) void k_prep(const float* __restrict__ pc,
    const float* __restrict__ G1, const float* __restrict__ G2,
    float4* __restrict__ pts4, unsigned short* __restrict__ G1b,
    unsigned short* __restrict__ G2b, unsigned* __restrict__ gmaxK) {
  int id = blockIdx.x * 256 + threadIdx.x;
  if (id < 32768) {
    int b = id >> 13, n = id & 8191;
    const float* pb = pc + (size_t)b * 3 * NPTS;
    float x = pb[n], y = pb[NPTS + n], z = pb[2 * NPTS + n];
    pts4[id] = make_float4(x, y, z, fmaf(x, x, fmaf(y, y, z * z)));
  } else if (id < 98304) {
    int i = id - 32768;                      // G2: 262144 f32 = 65536 x4
    float4 v = *(const float4*)(G2 + (size_t)i * 4);
    uint2 pk;
    pk.x = (unsigned)bf16rn(v.x) | ((unsigned)bf16rn(v.y) << 16);
    pk.y = (unsigned)bf16rn(v.z) | ((unsigned)bf16rn(v.w) << 16);
    *(uint2*)(G2b + (size_t)i * 4) = pk;
  } else if (id < 106496) {
    int i = id - 98304;                      // G1: 32768 f32 = 8192 x4
    float4 v = *(const float4*)(G1 + (size_t)i * 4);
    uint2 pk;
    pk.x = (unsigned)bf16rn(v.x) | ((unsigned)bf16rn(v.y) << 16);
    pk.y = (unsigned)bf16rn(v.z) | ((unsigned)bf16rn(v.w) << 16);
    *(uint2*)(G1b + (size_t)i * 4) = pk;
  } else if (id < 110592) {
    gmaxK[id - 106496] = 0u;
  }
}

// ---------- local encoder: lfT (f32) + lfB (bf16) ----------
__global__ __launch_bounds__(256) void k_local(const float* __restrict__ pc,
    const float* __restrict__ W1, const float* __restrict__ b1,
    const float* __restrict__ W2, const float* __restrict__ b2,
    float* __restrict__ lfT, unsigned short* __restrict__ lfB) {
  __shared__ float sW1[192], sb1[64], sW2[8192], sb2[128];
  int t = threadIdx.x;
  if (t < 192) sW1[t] = W1[t];
  if (t < 64) sb1[t] = b1[t];
  if (t < 128) sb2[t] = b2[t];
  for (int i = t; i < 8192; i += 256) sW2[i] = W2[i];
  __syncthreads();

  int gid = blockIdx.x * 256 + t;
  int b = gid >> 13;
  const float* base = pc + (size_t)b * 3 * NPTS + (gid & 8191);
  float x = base[0], y = base[NPTS], z = base[2 * NPTS];

  float h[64];
#pragma unroll
  for (int j = 0; j < 64; ++j) {
    float v = fmaf(sW1[j * 3 + 2], z, fmaf(sW1[j * 3 + 1], y, fmaf(sW1[j * 3], x, sb1[j])));
    h[j] = fmaxf(v, 0.f);
  }

  float* o = lfT + (size_t)gid * 128;
  unsigned short* ob = lfB + (size_t)gid * 128;
  for (int c = 0; c < 128; c += 4) {
    float a0 = sb2[c], a1 = sb2[c + 1], a2 = sb2[c + 2], a3 = sb2[c + 3];
#pragma unroll
    for (int j = 0; j < 64; j += 4) {
      float4 w0 = *(const float4*)&sW2[(c + 0) * 64 + j];
      float4 w1 = *(const float4*)&sW2[(c + 1) * 64 + j];
      float4 w2 = *(const float4*)&sW2[(c + 2) * 64 + j];
      float4 w3 = *(const float4*)&sW2[(c + 3) * 64 + j];
      a0 = fmaf(w0.x, h[j], fmaf(w0.y, h[j + 1], fmaf(w0.z, h[j + 2], fmaf(w0.w, h[j + 3], a0))));
      a1 = fmaf(w1.x, h[j], fmaf(w1.y, h[j + 1], fmaf(w1.z, h[j + 2], fmaf(w1.w, h[j + 3], a1))));
      a2 = fmaf(w2.x, h[j], fmaf(w2.y, h[j + 1], fmaf(w2.z, h[j + 2], fmaf(w2.w, h[j + 3], a2))));
      a3 = fmaf(w3.x, h[j], fmaf(w3.y, h[j + 1], fmaf(w3.z, h[j + 2], fmaf(w3.w, h[j + 3], a3))));
    }
    float4 r;
    r.x = fmaxf(a0, 0.f); r.y = fmaxf(a1, 0.f); r.z = fmaxf(a2, 0.f); r.w = fmaxf(a3, 0.f);
    *(float4*)&o[c] = r;
    uint2 pk;
    pk.x = (unsigned)bf16rn(r.x) | ((unsigned)bf16rn(r.y) << 16);
    pk.y = (unsigned)bf16rn(r.z) | ((unsigned)bf16rn(r.w) << 16);
    *(uint2*)&ob[c] = pk;
  }
}

// ---------- fused global encoder: g1 = relu(lfB.G1^T+b) in LDS, colmax(g1.G2^T) ----------
// Grid: 256 blocks x 128 rows. Phase1: each wave computes its 32 rows x 256 cols
// of g1 (bf16) into XOR-swizzled LDS. Phase2: each wave holds its 2x8 A-frags in
// registers (16 LDS reads total) and streams all 1024 G2 channels (L2-resident).
__global__ __launch_bounds__(256, 1) void k_genc(
    const unsigned short* __restrict__ lfB,
    const unsigned short* __restrict__ G1b, const float* __restrict__ g1bias,
    const unsigned short* __restrict__ G2b, const float* __restrict__ g2bias,
    unsigned* __restrict__ gmaxK) {
  __shared__ unsigned short g1s[128 * 256];   // 64 KB, swizzled
  __shared__ unsigned smax[1024];
  int t = threadIdx.x;
  int w = t >> 6, l = t & 63, lr = l & 15, lg = l >> 4;
  int mBase = blockIdx.x * 128;
  for (int i = t; i < 1024; i += 256) smax[i] = 0u;

  // ---- phase 1
  const unsigned short* arow = lfB + (size_t)(mBase + w * 32 + lr) * 128 + lg * 8;
  f32x4 acc0[16] = {};
  f32x4 acc1[16] = {};
#pragma unroll
  for (int ko = 0; ko < 128; ko += 32) {
    frag_ab a0 = *(const frag_ab*)(arow + ko);
    frag_ab a1 = *(const frag_ab*)(arow + 16 * 128 + ko);
#pragma unroll
    for (int ni = 0; ni < 16; ++ni) {
      frag_ab bb = *(const frag_ab*)(G1b + (size_t)(ni * 16 + lr) * 128 + lg * 8 + ko);
      acc0[ni] = __builtin_amdgcn_mfma_f32_16x16x32_bf16(a0, bb, acc0[ni], 0, 0, 0);
      acc1[ni] = __builtin_amdgcn_mfma_f32_16x16x32_bf16(a1, bb, acc1[ni], 0, 0, 0);
    }
  }
  char* g1c = (char*)g1s;
#pragma unroll
  for (int ni = 0; ni < 16; ++ni) {
    int col = ni * 16 + lr;
    float bb = g1bias[col];
#pragma unroll
    for (int r = 0; r < 4; ++r) {
      int row0 = w * 32 + lg * 4 + r;
      unsigned off0 = row0 * 512 + ((col * 2) ^ ((row0 & 7) << 4));
      *(unsigned short*)(g1c + off0) = bf16rn(fmaxf(acc0[ni][r] + bb, 0.f));
      int row1 = row0 + 16;
      unsigned off1 = row1 * 512 + ((col * 2) ^ ((row1 & 7) << 4));
      *(unsigned short*)(g1c + off1) = bf16rn(fmaxf(acc1[ni][r] + bb, 0.f));
    }
  }
  __syncthreads();

  // ---- phase 2: wave w rows w*32..+31, all 1024 channels
  frag_ab a[2][8];
#pragma unroll
  for (int mi = 0; mi < 2; ++mi) {
    int row = w * 32 + mi * 16 + lr;
#pragma unroll
    for (int k = 0; k < 8; ++k) {
      unsigned off = row * 512 + ((k * 64 + lg * 16) ^ ((row & 7) << 4));
      a[mi][k] = *(const frag_ab*)(g1c + off);
    }
  }
#pragma unroll 2
  for (int ni2 = 0; ni2 < 32; ++ni2) {
    const unsigned short* w0 = G2b + (size_t)(ni2 * 32 + lr) * 256 + lg * 8;
    frag_ab b0[8], b1[8];
#pragma unroll
    for (int k = 0; k < 8; ++k) {
      b0[k] = *(const frag_ab*)(w0 + k * 32);
      b1[k] = *(const frag_ab*)(w0 + 16 * 256 + k * 32);
    }
    f32x4 c00 = {}, c01 = {}, c10 = {}, c11 = {};
#pragma unroll
    for (int k = 0; k < 8; ++k) {
      c00 = __builtin_amdgcn_mfma_f32_16x16x32_bf16(a[0][k], b0[k], c00, 0, 0, 0);
      c01 = __builtin_amdgcn_mfma_f32_16x16x32_bf16(a[0][k], b1[k], c01, 0, 0, 0);
      c10 = __builtin_amdgcn_mfma_f32_16x16x32_bf16(a[1][k], b0[k], c10, 0, 0, 0);
      c11 = __builtin_amdgcn_mfma_f32_16x16x32_bf16(a[1][k], b1[k], c11, 0, 0, 0);
    }
    float v0 = fmaxf(fmaxf(fmaxf(c00[0], c00[1]), fmaxf(c00[2], c00[3])),
                     fmaxf(fmaxf(c10[0], c10[1]), fmaxf(c10[2], c10[3])));
    float v1 = fmaxf(fmaxf(fmaxf(c01[0], c01[1]), fmaxf(c01[2], c01[3])),
                     fmaxf(fmaxf(c11[0], c11[1]), fmaxf(c11[2], c11[3])));
    v0 = fmaxf(v0, __shfl_xor(v0, 16)); v0 = fmaxf(v0, __shfl_xor(v0, 32));
    v1 = fmaxf(v1, __shfl_xor(v1, 16)); v1 = fmaxf(v1, __shfl_xor(v1, 32));
    if (lg == 0) {
      atomicMax(&smax[ni2 * 32 + lr], fkey(v0));
      atomicMax(&smax[ni2 * 32 + 16 + lr], fkey(v1));
    }
  }
  __syncthreads();
  int bIdx = blockIdx.x >> 6;
  for (int i = t; i < 1024; i += 256) {
    float cm = funkey(smax[i]) + g2bias[i];
    atomicMax(&gmaxK[bIdx * 1024 + i], fkey(cm));
  }
}

// ---------- KNN A: 4 queries/thread, branchless f32 top-3 per (query, 256-chunk) ----------
__global__ __launch_bounds__(256) void k_knnA(const float4* __restrict__ pts4,
    const float* __restrict__ qp, float* __restrict__ pA) {
  int gq4 = blockIdx.x * 256 + threadIdx.x;   // 0..8191 (4 queries each)
  int b = blockIdx.x >> 3;                     // block-uniform batch
  int qi0 = (gq4 * 4) & 8191;
  int ch = blockIdx.y;                         // 0..31
  const float* qb = qp + (size_t)b * 3 * NPTS;
  float4 qx = *(const float4*)(qb + qi0);
  float4 qy = *(const float4*)(qb + NPTS + qi0);
  float4 qz = *(const float4*)(qb + 2 * NPTS + qi0);
  float tax[4] = {-2.f * qx.x, -2.f * qx.y, -2.f * qx.z, -2.f * qx.w};
  float tay[4] = {-2.f * qy.x, -2.f * qy.y, -2.f * qy.z, -2.f * qy.w};
  float taz[4] = {-2.f * qz.x, -2.f * qz.y, -2.f * qz.z, -2.f * qz.w};

  const float4* P = pts4 + (b << 13) + (ch << 8);
  float k0[4], k1[4], k2[4];
#pragma unroll
  for (int j = 0; j < 4; ++j) { k0[j] = FLT_MAX; k1[j] = FLT_MAX; k2[j] = FLT_MAX; }

  float4 a0 = P[0], a1 = P[1], a2 = P[2], a3 = P[3];
  for (int i = 0; i < 256; i += 4) {
    int nx = (i + 4) & 255;
    float4 n0 = P[nx], n1 = P[nx + 1], n2 = P[nx + 2], n3 = P[nx + 3];
#pragma unroll
    for (int c = 0; c < 4; ++c) {
      float4 p = (c == 0) ? a0 : (c == 1) ? a1 : (c == 2) ? a2 : a3;
#pragma unroll
      for (int j = 0; j < 4; ++j) {
        float e = fmaf(p.x, tax[j], fmaf(p.y, tay[j], fmaf(p.z, taz[j], p.w)));
        NET3(e, k0[j], k1[j], k2[j]);
      }
    }
    a0 = n0; a1 = n1; a2 = n2; a3 = n3;
  }
  float* pa = pA + ((size_t)gq4 * 32 + ch) * 12;
#pragma unroll
  for (int j = 0; j < 4; ++j) {
    pa[j * 3 + 0] = k0[j]; pa[j * 3 + 1] = k1[j]; pa[j * 3 + 2] = k2[j];
  }
}

// ---------- KNN gate: merge 32 chunk-partials -> tau + slack per query ----------
__global__ __launch_bounds__(256) void k_gate(const float* __restrict__ pA,
                                              float* __restrict__ gate) {
  int gq4 = blockIdx.x * 256 + threadIdx.x;   // 0..8191
  const float* pa = pA + (size_t)gq4 * 384;
  float g[4];
#pragma unroll
  for (int j = 0; j < 4; ++j) {
    float k0 = FLT_MAX, k1 = FLT_MAX, k2 = FLT_MAX;
    for (int ch = 0; ch < 32; ++ch) {
      float e0 = pa[ch * 12 + j * 3 + 0];
      float e1 = pa[ch * 12 + j * 3 + 1];
      float e2 = pa[ch * 12 + j * 3 + 2];
      NET3(e0, k0, k1, k2); NET3(e1, k0, k1, k2); NET3(e2, k0, k1, k2);
    }
    g[j] = k2 + 1e-3f;   // f32 eval band ~3e-5; 30x margin
  }
  *(float4*)(gate + (size_t)gq4 * 4) = make_float4(g[0], g[1], g[2], g[3]);
}

// ---------- KNN B: gated rescan; exact f64 top-3 per (query, 512-chunk), no atomics ----------
__global__ __launch_bounds__(256) void k_knnB(const float4* __restrict__ pts4,
    const float* __restrict__ qp, const float* __restrict__ gate,
    double* __restrict__ pd2, int* __restrict__ pi2) {
  int gq4 = blockIdx.x * 256 + threadIdx.x;
  int b = blockIdx.x >> 3;
  int qi0 = (gq4 * 4) & 8191;
  int ch = blockIdx.y;
  const float* qb = qp + (size_t)b * 3 * NPTS;
  float4 qx = *(const float4*)(qb + qi0);
  float4 qy = *(const float4*)(qb + NPTS + qi0);
  float4 qz = *(const float4*)(qb + 2 * NPTS + qi0);
  float tax[4] = {-2.f * qx.x, -2.f * qx.y, -2.f * qx.z, -2.f * qx.w};
  float tay[4] = {-2.f * qy.x, -2.f * qy.y, -2.f * qy.z, -2.f * qy.w};
  float taz[4] = {-2.f * qz.x, -2.f * qz.y, -2.f * qz.z, -2.f * qz.w};
  float qxs[4] = {qx.x, qx.y, qx.z, qx.w};
  float qys[4] = {qy.x, qy.y, qy.z, qy.w};
  float qzs[4] = {qz.x, qz.y, qz.z, qz.w};
  float4 g4 = *(const float4*)(gate + (size_t)gq4 * 4);
  float gt[4] = {g4.x, g4.y, g4.z, g4.w};

  double d0[4], d1[4], d2[4];
  int i0[4], i1[4], i2[4];
#pragma unroll
  for (int j = 0; j < 4; ++j) {
    d0[j] = 1e300; d1[j] = 1e300; d2[j] = 1e300;
    i0[j] = 0; i1[j] = 0; i2[j] = 0;
  }

  const float4* P = pts4 + (b << 13) + (ch << 9);
  int nb = ch << 9;
  float4 a0 = P[0], a1 = P[1], a2 = P[2], a3 = P[3];
  for (int i = 0; i < 512; i += 4) {
    int nx = (i + 4) & 511;
    float4 n0 = P[nx], n1 = P[nx + 1], n2 = P[nx + 2], n3 = P[nx + 3];
#pragma unroll
    for (int j = 0; j < 4; ++j) {
      float e0 = fmaf(a0.x, tax[j], fmaf(a0.y, tay[j], fmaf(a0.z, taz[j], a0.w)));
      float e1 = fmaf(a1.x, tax[j], fmaf(a1.y, tay[j], fmaf(a1.z, taz[j], a1.w)));
      float e2 = fmaf(a2.x, tax[j], fmaf(a2.y, tay[j], fmaf(a2.z, taz[j], a2.w)));
      float e3 = fmaf(a3.x, tax[j], fmaf(a3.y, tay[j], fmaf(a3.z, taz[j], a3.w)));
      float mn = fminf(fminf(e0, e1), fminf(e2, e3));
      if (mn <= gt[j]) {                      // rare
        double tax64 = -2.0 * (double)qxs[j];
        double tay64 = -2.0 * (double)qys[j];
        double taz64 = -2.0 * (double)qzs[j];
#pragma unroll
        for (int c = 0; c < 4; ++c) {
          float ec = (c == 0) ? e0 : (c == 1) ? e1 : (c == 2) ? e2 : e3;
          float4 p = (c == 0) ? a0 : (c == 1) ? a1 : (c == 2) ? a2 : a3;
          if (ec <= gt[j]) {
            double cx = (double)p.x, cy = (double)p.y, cz = (double)p.z;
            double pp = fma(cx, cx, fma(cy, cy, cz * cz));
            double e64 = fma(cx, tax64, fma(cy, tay64, fma(cz, taz64, pp)));
            int n = nb + i + c;
            if (e64 < d2[j]) {                // strict <: scan order = index order
              if (e64 < d1[j]) {
                d2[j] = d1[j]; i2[j] = i1[j];
                if (e64 < d0[j]) { d1[j] = d0[j]; i1[j] = i0[j]; d0[j] = e64; i0[j] = n; }
                else { d1[j] = e64; i1[j] = n; }
              } else { d2[j] = e64; i2[j] = n; }
            }
          }
        }
      }
    }
    a0 = n0; a1 = n1; a2 = n2; a3 = n3;
  }

  double* pdq = pd2 + ((size_t)gq4 * 16 + ch) * 12;
  int* piq = pi2 + ((size_t)gq4 * 16 + ch) * 12;
#pragma unroll
  for (int j = 0; j < 4; ++j) {
    pdq[j * 3 + 0] = d0[j]; pdq[j * 3 + 1] = d1[j]; pdq[j * 3 + 2] = d2[j];
    piq[j * 3 + 0] = i0[j]; piq[j * 3 + 1] = i1[j]; piq[j * 3 + 2] = i2[j];
  }
}

// ---------- KNN C: merge 16 chunk-partials (chunk order = index order, strict <) ----------
__global__ __launch_bounds__(256) void k_knnC(const double* __restrict__ pd2,
    const int* __restrict__ pi2, int* __restrict__ ids) {
  int q = blockIdx.x * 256 + threadIdx.x;
  int gq4 = q >> 2, j = q & 3;
  double d0 = 1e300, d1 = 1e300, d2v = 1e300;
  int i0 = 0, i1 = 0, i2 = 0;
  for (int ch = 0; ch < 16; ++ch) {
    const double* pdq = pd2 + ((size_t)gq4 * 16 + ch) * 12 + j * 3;
    const int* piq = pi2 + ((size_t)gq4 * 16 + ch) * 12 + j * 3;
#pragma unroll
    for (int k = 0; k < 3; ++k) {
      double d = pdq[k];
      int n = piq[k];
      if (d < d2v) {
        if (d < d1) {
          d2v = d1; i2 = i1;
          if (d < d0) { d1 = d0; i1 = i0; d0 = d; i0 = n; }
          else { d1 = d; i1 = n; }
        } else { d2v = d; i2 = n; }
      }
    }
  }
  ids[q * 4 + 0] = i0; ids[q * 4 + 1] = i1; ids[q * 4 + 2] = i2;
}

// ---------- fused output: bcast gmax (ch<1024) + gather (ch 1024..1151) ----------
__global__ __launch_bounds__(256) void k_out(const unsigned* __restrict__ gmaxK,
    const float* __restrict__ lfT, const int* __restrict__ ids,
    float* __restrict__ out) {
  int bid = blockIdx.x;
  int t = threadIdx.x;
  if (bid < 32768) {
    int id = bid * 256 + t;                  // float4 index
    int m4 = id & 2047;
    int c = (id >> 11) & 1023;
    int b = id >> 21;
    float v = funkey(gmaxK[b * 1024 + c]);
    *(float4*)(out + ((size_t)(b * 1152 + c) << 13) + (m4 << 2)) = make_float4(v, v, v, v);
  } else {
    int bid2 = bid - 32768;
    int b = bid2 >> 7, mb = bid2 & 127;
    int m = mb * 64 + (t & 63);
    int cg = t >> 6;
    int q = b * NQ + m;
    int ia = ids[q * 4 + 0], ib = ids[q * 4 + 1], ic = ids[q * 4 + 2];
    const float* f0 = lfT + ((size_t)b * NPTS + ia) * 128;
    const float* f1 = lfT + ((size_t)b * NPTS + ib) * 128;
    const float* f2 = lfT + ((size_t)b * NPTS + ic) * 128;
    float* ob = out + ((size_t)(b * 1152 + 1024)) * (size_t)NQ + m;
    const float s = 1.f / 3.f;
#pragma unroll
    for (int c4 = 0; c4 < 32; c4 += 4) {
      int c = cg * 32 + c4;
      float4 v0 = *(const float4*)(f0 + c);
      float4 v1 = *(const float4*)(f1 + c);
      float4 v2 = *(const float4*)(f2 + c);
      ob[(size_t)(c + 0) * NQ] = ((v0.x + v1.x) + v2.x) * s;
      ob[(size_t)(c + 1) * NQ] = ((v0.y + v1.y) + v2.y) * s;
      ob[(size_t)(c + 2) * NQ] = ((v0.z + v1.z) + v2.z) * s;
      ob[(size_t)(c + 3) * NQ] = ((v0.w + v1.w) + v2.w) * s;
    }
  }
}

extern "C" void kernel_launch(void* const* d_in, const int* in_sizes, int n_in,
                              void* d_out, int out_size, void* d_ws, size_t ws_size,
                              hipStream_t stream) {
  const float* pc  = (const float*)d_in[0];
  const float* qp  = (const float*)d_in[1];
  const float* W1  = (const float*)d_in[2];
  const float* b1  = (const float*)d_in[3];
  const float* W2  = (const float*)d_in[4];
  const float* b2  = (const float*)d_in[5];
  const float* G1  = (const float*)d_in[6];
  const float* g1b = (const float*)d_in[7];
  const float* G2  = (const float*)d_in[8];
  const float* g2b = (const float*)d_in[9];
  float* out = (float*)d_out;

  char* ws = (char*)d_ws;
  // persistent:
  float*          lfT   = (float*)(ws + 0);                  // 16 MB [B][N][128] f32
  float*          gate  = (float*)(ws + 48234496);           // 128 KB [32768]
  int*            ids   = (int*)(ws + 48365568);             // 512 KB
  float4*         pts4  = (float4*)(ws + 48889856);          // 512 KB
  unsigned short* G1b16 = (unsigned short*)(ws + 49414144);  // 64 KB
  unsigned short* G2b16 = (unsigned short*)(ws + 49479680);  // 512 KB
  unsigned*       gmaxK = (unsigned*)(ws + 50003968);        // 16 KB -> end 50,020,352
  // KNN scratch (dead after k_knnC):
  float*          pA    = (float*)(ws + 16777216);           // 12.6 MB [8192][32][12]
  double*         pd2   = (double*)(ws + 29360128);          // 12.6 MB [8192][16][12] f64
  int*            pi2   = (int*)(ws + 41943040);             // 6.3 MB
  // encoder tensor (aliases pA; written after knn done):
  unsigned short* lfB   = (unsigned short*)(ws + 16777216);  // 8 MB [32768][128] bf16

  k_prep<<<432, 256, 0, stream>>>(pc, G1, G2, pts4, G1b16, G2b16, gmaxK);
  k_knnA<<<dim3(32, 32), 256, 0, stream>>>(pts4, qp, pA);
  k_gate<<<32, 256, 0, stream>>>(pA, gate);
  k_knnB<<<dim3(32, 16), 256, 0, stream>>>(pts4, qp, gate, pd2, pi2);
  k_knnC<<<128, 256, 0, stream>>>(pd2, pi2, ids);
  k_local<<<128, 256, 0, stream>>>(pc, W1, b1, W2, b2, lfT, lfB);
  k_genc<<<256, 256, 0, stream>>>(lfB, G1b16, g1b, G2b16, g2b, gmaxK);
  k_out<<<33280, 256, 0, stream>>>(gmaxK, lfT, ids, out);
}

// Round 7
// 284.060 us; speedup vs baseline: 1.6041x; 1.1660x over previous
//
#include <hip/hip_runtime.h>
#include <float.h>

#define NPTS 8192
#define NB 4
#define NQ 8192

using frag_ab = __attribute__((ext_vector_type(8))) short;   // 8 bf16 (4 VGPRs)
using f32x4   = __attribute__((ext_vector_type(4))) float;

// ---------- monotone float<->uint key for atomic max over floats ----------
__device__ __forceinline__ unsigned fkey(float f) {
  unsigned u = __float_as_uint(f);
  return (u & 0x80000000u) ? ~u : (u | 0x80000000u);
}
__device__ __forceinline__ float funkey(unsigned k) {
  unsigned u = (k & 0x80000000u) ? (k & 0x7fffffffu) : ~k;
  return __uint_as_float(u);
}
__device__ __forceinline__ unsigned short bf16rn(float f) {
  unsigned u = __float_as_uint(f);
  return (unsigned short)((u + 0x7fffu + ((u >> 16) & 1u)) >> 16);
}

// sorted-insert network for top-3 smallest (values only)
#define NET3(e, k0, k1, k2)                                           \
  {                                                                   \
    float nk2 = __builtin_amdgcn_fmed3f(k2, k1, (e));                 \
    float nk1 = __builtin_amdgcn_fmed3f(k1, k0, (e));                 \
    k0 = fminf(k0, (e));                                              \
    k1 = nk1; k2 = nk2;                                               \
  }

// ---------- prep: pack pts4 + cast G1/G2 -> bf16 + init gmax keys ----------
__global__ __launch_bounds__(256) void k_prep(const float* __restrict__ pc,
    const float* __restrict__ G1, const float* __restrict__ G2,
    float4* __restrict__ pts4, unsigned short* __restrict__ G1b,
    unsigned short* __restrict__ G2b, unsigned* __restrict__ gmaxK) {
  int id = blockIdx.x * 256 + threadIdx.x;
  if (id < 32768) {
    int b = id >> 13, n = id & 8191;
    const float* pb = pc + (size_t)b * 3 * NPTS;
    float x = pb[n], y = pb[NPTS + n], z = pb[2 * NPTS + n];
    pts4[id] = make_float4(x, y, z, fmaf(x, x, fmaf(y, y, z * z)));
  } else if (id < 98304) {
    int i = id - 32768;                      // G2: 262144 f32 = 65536 x4
    float4 v = *(const float4*)(G2 + (size_t)i * 4);
    uint2 pk;
    pk.x = (unsigned)bf16rn(v.x) | ((unsigned)bf16rn(v.y) << 16);
    pk.y = (unsigned)bf16rn(v.z) | ((unsigned)bf16rn(v.w) << 16);
    *(uint2*)(G2b + (size_t)i * 4) = pk;
  } else if (id < 106496) {
    int i = id - 98304;                      // G1: 32768 f32 = 8192 x4
    float4 v = *(const float4*)(G1 + (size_t)i * 4);
    uint2 pk;
    pk.x = (unsigned)bf16rn(v.x) | ((unsigned)bf16rn(v.y) << 16);
    pk.y = (unsigned)bf16rn(v.z) | ((unsigned)bf16rn(v.w) << 16);
    *(uint2*)(G1b + (size_t)i * 4) = pk;
  } else if (id < 110592) {
    gmaxK[id - 106496] = 0u;
  }
}

// ---------- local encoder: lfT (f32) + lfB (bf16) ----------
__global__ __launch_bounds__(256) void k_local(const float* __restrict__ pc,
    const float* __restrict__ W1, const float* __restrict__ b1,
    const float* __restrict__ W2, const float* __restrict__ b2,
    float* __restrict__ lfT, unsigned short* __restrict__ lfB) {
  __shared__ float sW1[192], sb1[64], sW2[8192], sb2[128];
  int t = threadIdx.x;
  if (t < 192) sW1[t] = W1[t];
  if (t < 64) sb1[t] = b1[t];
  if (t < 128) sb2[t] = b2[t];
  for (int i = t; i < 8192; i += 256) sW2[i] = W2[i];
  __syncthreads();

  int gid = blockIdx.x * 256 + t;
  int b = gid >> 13;
  const float* base = pc + (size_t)b * 3 * NPTS + (gid & 8191);
  float x = base[0], y = base[NPTS], z = base[2 * NPTS];

  float h[64];
#pragma unroll
  for (int j = 0; j < 64; ++j) {
    float v = fmaf(sW1[j * 3 + 2], z, fmaf(sW1[j * 3 + 1], y, fmaf(sW1[j * 3], x, sb1[j])));
    h[j] = fmaxf(v, 0.f);
  }

  float* o = lfT + (size_t)gid * 128;
  unsigned short* ob = lfB + (size_t)gid * 128;
  for (int c = 0; c < 128; c += 4) {
    float a0 = sb2[c], a1 = sb2[c + 1], a2 = sb2[c + 2], a3 = sb2[c + 3];
#pragma unroll
    for (int j = 0; j < 64; j += 4) {
      float4 w0 = *(const float4*)&sW2[(c + 0) * 64 + j];
      float4 w1 = *(const float4*)&sW2[(c + 1) * 64 + j];
      float4 w2 = *(const float4*)&sW2[(c + 2) * 64 + j];
      float4 w3 = *(const float4*)&sW2[(c + 3) * 64 + j];
      a0 = fmaf(w0.x, h[j], fmaf(w0.y, h[j + 1], fmaf(w0.z, h[j + 2], fmaf(w0.w, h[j + 3], a0))));
      a1 = fmaf(w1.x, h[j], fmaf(w1.y, h[j + 1], fmaf(w1.z, h[j + 2], fmaf(w1.w, h[j + 3], a1))));
      a2 = fmaf(w2.x, h[j], fmaf(w2.y, h[j + 1], fmaf(w2.z, h[j + 2], fmaf(w2.w, h[j + 3], a2))));
      a3 = fmaf(w3.x, h[j], fmaf(w3.y, h[j + 1], fmaf(w3.z, h[j + 2], fmaf(w3.w, h[j + 3], a3))));
    }
    float4 r;
    r.x = fmaxf(a0, 0.f); r.y = fmaxf(a1, 0.f); r.z = fmaxf(a2, 0.f); r.w = fmaxf(a3, 0.f);
    *(float4*)&o[c] = r;
    uint2 pk;
    pk.x = (unsigned)bf16rn(r.x) | ((unsigned)bf16rn(r.y) << 16);
    pk.y = (unsigned)bf16rn(r.z) | ((unsigned)bf16rn(r.w) << 16);
    *(uint2*)&ob[c] = pk;
  }
}

// ---------- fused global encoder v2 ----------
// Grid: 512 blocks x 64 rows, 512 threads (8 waves). LDS 32 KB.
// Phase 1 (operand-swapped): wave w computes tile (rb=w&3, cols (w>>2)*128..+127)
//   of g1; lane holds 4 consecutive g1 COLS of one row -> one ds_write_b64 each.
// Phase 2: wave w owns output cols w*128..+127; A-frags (all 64 rows) live in
//   128 VGPRs loaded once from LDS; each G2 Y-frag feeds 4 MFMAs; G2 read once
//   per block (L2-hot). Column max -> global atomicMax (bias added in k_out).
__global__ __launch_bounds__(512, 2) void k_genc(
    const unsigned short* __restrict__ lfB,
    const unsigned short* __restrict__ G1b, const float* __restrict__ g1bias,
    const unsigned short* __restrict__ G2b, unsigned* __restrict__ gmaxK) {
  __shared__ char g1c[64 * 512];   // [64 rows][256 bf16 cols], XOR-swizzled
  int t = threadIdx.x;
  int w = t >> 6, l = t & 63, lr = l & 15, lg = l >> 4;
  int mBase = blockIdx.x * 64;

  // ---- phase 1
  int rb = w & 3, cbg = w >> 2;
  const unsigned short* yrow = lfB + (size_t)(mBase + rb * 16 + lr) * 128 + lg * 8;
  f32x4 acc1[8] = {};
#pragma unroll
  for (int ko = 0; ko < 4; ++ko) {
    frag_ab yf = *(const frag_ab*)(yrow + ko * 32);
#pragma unroll
    for (int i = 0; i < 8; ++i) {
      int cb = cbg * 8 + i;
      frag_ab xf = *(const frag_ab*)(G1b + (size_t)(cb * 16 + lr) * 128 + ko * 32 + lg * 8);
      acc1[i] = __builtin_amdgcn_mfma_f32_16x16x32_bf16(xf, yf, acc1[i], 0, 0, 0);
    }
  }
  {
    int mloc = rb * 16 + lr;                 // lane's g1 row (= Y-operand nonK idx)
    unsigned swz = (unsigned)((mloc & 7) << 4);
#pragma unroll
    for (int i = 0; i < 8; ++i) {
      int n0 = (cbg * 8 + i) * 16 + lg * 4;  // 4 consecutive g1 cols
      float4 bs = *(const float4*)(g1bias + n0);
      unsigned short p0 = bf16rn(fmaxf(acc1[i][0] + bs.x, 0.f));
      unsigned short p1 = bf16rn(fmaxf(acc1[i][1] + bs.y, 0.f));
      unsigned short p2 = bf16rn(fmaxf(acc1[i][2] + bs.z, 0.f));
      unsigned short p3 = bf16rn(fmaxf(acc1[i][3] + bs.w, 0.f));
      uint2 pk;
      pk.x = (unsigned)p0 | ((unsigned)p1 << 16);
      pk.y = (unsigned)p2 | ((unsigned)p3 << 16);
      unsigned off = (unsigned)(mloc * 512) + (((unsigned)(n0 * 2)) ^ swz);
      *(uint2*)(g1c + off) = pk;
    }
  }
  __syncthreads();

  // ---- phase 2
  frag_ab a[4][8];
#pragma unroll
  for (int mb = 0; mb < 4; ++mb) {
    int row = mb * 16 + lr;
    unsigned sz = (unsigned)((row & 7) << 4);
#pragma unroll
    for (int ks = 0; ks < 8; ++ks)
      a[mb][ks] = *(const frag_ab*)(g1c + row * 512 + (((unsigned)(ks * 64 + lg * 16)) ^ sz));
  }
  int bIdx = blockIdx.x >> 7;
#pragma unroll 2
  for (int cb2 = 0; cb2 < 8; ++cb2) {
    int n = w * 128 + cb2 * 16 + lr;
    const unsigned short* yb = G2b + (size_t)n * 256 + lg * 8;
    f32x4 c0 = {}, c1 = {}, c2 = {}, c3 = {};
#pragma unroll
    for (int ks = 0; ks < 8; ++ks) {
      frag_ab yf = *(const frag_ab*)(yb + ks * 32);
      c0 = __builtin_amdgcn_mfma_f32_16x16x32_bf16(a[0][ks], yf, c0, 0, 0, 0);
      c1 = __builtin_amdgcn_mfma_f32_16x16x32_bf16(a[1][ks], yf, c1, 0, 0, 0);
      c2 = __builtin_amdgcn_mfma_f32_16x16x32_bf16(a[2][ks], yf, c2, 0, 0, 0);
      c3 = __builtin_amdgcn_mfma_f32_16x16x32_bf16(a[3][ks], yf, c3, 0, 0, 0);
    }
    float v = fmaxf(fmaxf(fmaxf(c0[0], c0[1]), fmaxf(c0[2], c0[3])),
                    fmaxf(fmaxf(c1[0], c1[1]), fmaxf(c1[2], c1[3])));
    v = fmaxf(v, fmaxf(fmaxf(fmaxf(c2[0], c2[1]), fmaxf(c2[2], c2[3])),
                       fmaxf(fmaxf(c3[0], c3[1]), fmaxf(c3[2], c3[3]))));
    v = fmaxf(v, __shfl_xor(v, 16));
    v = fmaxf(v, __shfl_xor(v, 32));
    if (lg == 0) atomicMax(&gmaxK[bIdx * 1024 + n], fkey(v));
  }
}

// ---------- KNN A: 4 queries/thread, branchless f32 top-3 per (query, 256-chunk) ----------
__global__ __launch_bounds__(256) void k_knnA(const float4* __restrict__ pts4,
    const float* __restrict__ qp, float* __restrict__ pA) {
  int gq4 = blockIdx.x * 256 + threadIdx.x;   // 0..8191 (4 queries each)
  int b = blockIdx.x >> 3;                     // block-uniform batch
  int qi0 = (gq4 * 4) & 8191;
  int ch = blockIdx.y;                         // 0..31
  const float* qb = qp + (size_t)b * 3 * NPTS;
  float4 qx = *(const float4*)(qb + qi0);
  float4 qy = *(const float4*)(qb + NPTS + qi0);
  float4 qz = *(const float4*)(qb + 2 * NPTS + qi0);
  float tax[4] = {-2.f * qx.x, -2.f * qx.y, -2.f * qx.z, -2.f * qx.w};
  float tay[4] = {-2.f * qy.x, -2.f * qy.y, -2.f * qy.z, -2.f * qy.w};
  float taz[4] = {-2.f * qz.x, -2.f * qz.y, -2.f * qz.z, -2.f * qz.w};

  const float4* P = pts4 + (b << 13) + (ch << 8);
  float k0[4], k1[4], k2[4];
#pragma unroll
  for (int j = 0; j < 4; ++j) { k0[j] = FLT_MAX; k1[j] = FLT_MAX; k2[j] = FLT_MAX; }

  float4 a0 = P[0], a1 = P[1], a2 = P[2], a3 = P[3];
  for (int i = 0; i < 256; i += 4) {
    int nx = (i + 4) & 255;
    float4 n0 = P[nx], n1 = P[nx + 1], n2 = P[nx + 2], n3 = P[nx + 3];
#pragma unroll
    for (int c = 0; c < 4; ++c) {
      float4 p = (c == 0) ? a0 : (c == 1) ? a1 : (c == 2) ? a2 : a3;
#pragma unroll
      for (int j = 0; j < 4; ++j) {
        float e = fmaf(p.x, tax[j], fmaf(p.y, tay[j], fmaf(p.z, taz[j], p.w)));
        NET3(e, k0[j], k1[j], k2[j]);
      }
    }
    a0 = n0; a1 = n1; a2 = n2; a3 = n3;
  }
  float* pa = pA + ((size_t)gq4 * 32 + ch) * 12;
#pragma unroll
  for (int j = 0; j < 4; ++j) {
    pa[j * 3 + 0] = k0[j]; pa[j * 3 + 1] = k1[j]; pa[j * 3 + 2] = k2[j];
  }
}

// ---------- KNN gate: merge 32 chunk-partials -> tau + slack per query ----------
__global__ __launch_bounds__(256) void k_gate(const float* __restrict__ pA,
                                              float* __restrict__ gate) {
  int gq4 = blockIdx.x * 256 + threadIdx.x;   // 0..8191
  const float* pa = pA + (size_t)gq4 * 384;
  float g[4];
#pragma unroll
  for (int j = 0; j < 4; ++j) {
    float k0 = FLT_MAX, k1 = FLT_MAX, k2 = FLT_MAX;
    for (int ch = 0; ch < 32; ++ch) {
      float e0 = pa[ch * 12 + j * 3 + 0];
      float e1 = pa[ch * 12 + j * 3 + 1];
      float e2 = pa[ch * 12 + j * 3 + 2];
      NET3(e0, k0, k1, k2); NET3(e1, k0, k1, k2); NET3(e2, k0, k1, k2);
    }
    g[j] = k2 + 1e-3f;   // f32 eval band ~3e-5; 30x margin
  }
  *(float4*)(gate + (size_t)gq4 * 4) = make_float4(g[0], g[1], g[2], g[3]);
}

// ---------- KNN B: gated rescan; exact f64 top-3 per (query, 512-chunk), no atomics ----------
__global__ __launch_bounds__(256) void k_knnB(const float4* __restrict__ pts4,
    const float* __restrict__ qp, const float* __restrict__ gate,
    double* __restrict__ pd2, int* __restrict__ pi2) {
  int gq4 = blockIdx.x * 256 + threadIdx.x;
  int b = blockIdx.x >> 3;
  int qi0 = (gq4 * 4) & 8191;
  int ch = blockIdx.y;
  const float* qb = qp + (size_t)b * 3 * NPTS;
  float4 qx = *(const float4*)(qb + qi0);
  float4 qy = *(const float4*)(qb + NPTS + qi0);
  float4 qz = *(const float4*)(qb + 2 * NPTS + qi0);
  float tax[4] = {-2.f * qx.x, -2.f * qx.y, -2.f * qx.z, -2.f * qx.w};
  float tay[4] = {-2.f * qy.x, -2.f * qy.y, -2.f * qy.z, -2.f * qy.w};
  float taz[4] = {-2.f * qz.x, -2.f * qz.y, -2.f * qz.z, -2.f * qz.w};
  float qxs[4] = {qx.x, qx.y, qx.z, qx.w};
  float qys[4] = {qy.x, qy.y, qy.z, qy.w};
  float qzs[4] = {qz.x, qz.y, qz.z, qz.w};
  float4 g4 = *(const float4*)(gate + (size_t)gq4 * 4);
  float gt[4] = {g4.x, g4.y, g4.z, g4.w};

  double d0[4], d1[4], d2[4];
  int i0[4], i1[4], i2[4];
#pragma unroll
  for (int j = 0; j < 4; ++j) {
    d0[j] = 1e300; d1[j] = 1e300; d2[j] = 1e300;
    i0[j] = 0; i1[j] = 0; i2[j] = 0;
  }

  const float4* P = pts4 + (b << 13) + (ch << 9);
  int nb = ch << 9;
  float4 a0 = P[0], a1 = P[1], a2 = P[2], a3 = P[3];
  for (int i = 0; i < 512; i += 4) {
    int nx = (i + 4) & 511;
    float4 n0 = P[nx], n1 = P[nx + 1], n2 = P[nx + 2], n3 = P[nx + 3];
#pragma unroll
    for (int j = 0; j < 4; ++j) {
      float e0 = fmaf(a0.x, tax[j], fmaf(a0.y, tay[j], fmaf(a0.z, taz[j], a0.w)));
      float e1 = fmaf(a1.x, tax[j], fmaf(a1.y, tay[j], fmaf(a1.z, taz[j], a1.w)));
      float e2 = fmaf(a2.x, tax[j], fmaf(a2.y, tay[j], fmaf(a2.z, taz[j], a2.w)));
      float e3 = fmaf(a3.x, tax[j], fmaf(a3.y, tay[j], fmaf(a3.z, taz[j], a3.w)));
      float mn = fminf(fminf(e0, e1), fminf(e2, e3));
      if (mn <= gt[j]) {                      // rare
        double tax64 = -2.0 * (double)qxs[j];
        double tay64 = -2.0 * (double)qys[j];
        double taz64 = -2.0 * (double)qzs[j];
#pragma unroll
        for (int c = 0; c < 4; ++c) {
          float ec = (c == 0) ? e0 : (c == 1) ? e1 : (c == 2) ? e2 : e3;
          float4 p = (c == 0) ? a0 : (c == 1) ? a1 : (c == 2) ? a2 : a3;
          if (ec <= gt[j]) {
            double cx = (double)p.x, cy = (double)p.y, cz = (double)p.z;
            double pp = fma(cx, cx, fma(cy, cy, cz * cz));
            double e64 = fma(cx, tax64, fma(cy, tay64, fma(cz, taz64, pp)));
            int n = nb + i + c;
            if (e64 < d2[j]) {                // strict <: scan order = index order
              if (e64 < d1[j]) {
                d2[j] = d1[j]; i2[j] = i1[j];
                if (e64 < d0[j]) { d1[j] = d0[j]; i1[j] = i0[j]; d0[j] = e64; i0[j] = n; }
                else { d1[j] = e64; i1[j] = n; }
              } else { d2[j] = e64; i2[j] = n; }
            }
          }
        }
      }
    }
    a0 = n0; a1 = n1; a2 = n2; a3 = n3;
  }

  double* pdq = pd2 + ((size_t)gq4 * 16 + ch) * 12;
  int* piq = pi2 + ((size_t)gq4 * 16 + ch) * 12;
#pragma unroll
  for (int j = 0; j < 4; ++j) {
    pdq[j * 3 + 0] = d0[j]; pdq[j * 3 + 1] = d1[j]; pdq[j * 3 + 2] = d2[j];
    piq[j * 3 + 0] = i0[j]; piq[j * 3 + 1] = i1[j]; piq[j * 3 + 2] = i2[j];
  }
}

// ---------- KNN C: merge 16 chunk-partials (chunk order = index order, strict <) ----------
__global__ __launch_bounds__(256) void k_knnC(const double* __restrict__ pd2,
    const int* __restrict__ pi2, int* __restrict__ ids) {
  int q = blockIdx.x * 256 + threadIdx.x;
  int gq4 = q >> 2, j = q & 3;
  double d0 = 1e300, d1 = 1e300, d2v = 1e300;
  int i0 = 0, i1 = 0, i2 = 0;
  for (int ch = 0; ch < 16; ++ch) {
    const double* pdq = pd2 + ((size_t)gq4 * 16 + ch) * 12 + j * 3;
    const int* piq = pi2 + ((size_t)gq4 * 16 + ch) * 12 + j * 3;
#pragma unroll
    for (int k = 0; k < 3; ++k) {
      double d = pdq[k];
      int n = piq[k];
      if (d < d2v) {
        if (d < d1) {
          d2v = d1; i2 = i1;
          if (d < d0) { d1 = d0; i1 = i0; d0 = d; i0 = n; }
          else { d1 = d; i1 = n; }
        } else { d2v = d; i2 = n; }
      }
    }
  }
  ids[q * 4 + 0] = i0; ids[q * 4 + 1] = i1; ids[q * 4 + 2] = i2;
}

// ---------- fused output: bcast gmax+bias (ch<1024) + gather (ch 1024..1151) ----------
__global__ __launch_bounds__(256) void k_out(const unsigned* __restrict__ gmaxK,
    const float* __restrict__ g2bias, const float* __restrict__ lfT,
    const int* __restrict__ ids, float* __restrict__ out) {
  int bid = blockIdx.x;
  int t = threadIdx.x;
  if (bid < 32768) {
    int id = bid * 256 + t;                  // float4 index
    int m4 = id & 2047;
    int c = (id >> 11) & 1023;
    int b = id >> 21;
    float v = funkey(gmaxK[b * 1024 + c]) + g2bias[c];
    *(float4*)(out + ((size_t)(b * 1152 + c) << 13) + (m4 << 2)) = make_float4(v, v, v, v);
  } else {
    int bid2 = bid - 32768;
    int b = bid2 >> 7, mb = bid2 & 127;
    int m = mb * 64 + (t & 63);
    int cg = t >> 6;
    int q = b * NQ + m;
    int ia = ids[q * 4 + 0], ib = ids[q * 4 + 1], ic = ids[q * 4 + 2];
    const float* f0 = lfT + ((size_t)b * NPTS + ia) * 128;
    const float* f1 = lfT + ((size_t)b * NPTS + ib) * 128;
    const float* f2 = lfT + ((size_t)b * NPTS + ic) * 128;
    float* ob = out + ((size_t)(b * 1152 + 1024)) * (size_t)NQ + m;
    const float s = 1.f / 3.f;
#pragma unroll
    for (int c4 = 0; c4 < 32; c4 += 4) {
      int c = cg * 32 + c4;
      float4 v0 = *(const float4*)(f0 + c);
      float4 v1 = *(const float4*)(f1 + c);
      float4 v2 = *(const float4*)(f2 + c);
      ob[(size_t)(c + 0) * NQ] = ((v0.x + v1.x) + v2.x) * s;
      ob[(size_t)(c + 1) * NQ] = ((v0.y + v1.y) + v2.y) * s;
      ob[(size_t)(c + 2) * NQ] = ((v0.z + v1.z) + v2.z) * s;
      ob[(size_t)(c + 3) * NQ] = ((v0.w + v1.w) + v2.w) * s;
    }
  }
}

extern "C" void kernel_launch(void* const* d_in, const int* in_sizes, int n_in,
                              void* d_out, int out_size, void* d_ws, size_t ws_size,
                              hipStream_t stream) {
  const float* pc  = (const float*)d_in[0];
  const float* qp  = (const float*)d_in[1];
  const float* W1  = (const float*)d_in[2];
  const float* b1  = (const float*)d_in[3];
  const float* W2  = (const float*)d_in[4];
  const float* b2  = (const float*)d_in[5];
  const float* G1  = (const float*)d_in[6];
  const float* g1b = (const float*)d_in[7];
  const float* G2  = (const float*)d_in[8];
  const float* g2b = (const float*)d_in[9];
  float* out = (float*)d_out;

  char* ws = (char*)d_ws;
  // persistent:
  float*          lfT   = (float*)(ws + 0);                  // 16 MB [B][N][128] f32
  float*          gate  = (float*)(ws + 48234496);           // 128 KB [32768]
  int*            ids   = (int*)(ws + 48365568);             // 512 KB
  float4*         pts4  = (float4*)(ws + 48889856);          // 512 KB
  unsigned short* G1b16 = (unsigned short*)(ws + 49414144);  // 64 KB
  unsigned short* G2b16 = (unsigned short*)(ws + 49479680);  // 512 KB
  unsigned*       gmaxK = (unsigned*)(ws + 50003968);        // 16 KB -> end 50,020,352
  // KNN scratch (dead after k_knnC):
  float*          pA    = (float*)(ws + 16777216);           // 12.6 MB [8192][32][12]
  double*         pd2   = (double*)(ws + 29360128);          // 12.6 MB [8192][16][12] f64
  int*            pi2   = (int*)(ws + 41943040);             // 6.3 MB
  // encoder tensor (aliases pA; written after knn done):
  unsigned short* lfB   = (unsigned short*)(ws + 16777216);  // 8 MB [32768][128] bf16

  k_prep<<<432, 256, 0, stream>>>(pc, G1, G2, pts4, G1b16, G2b16, gmaxK);
  k_knnA<<<dim3(32, 32), 256, 0, stream>>>(pts4, qp, pA);
  k_gate<<<32, 256, 0, stream>>>(pA, gate);
  k_knnB<<<dim3(32, 16), 256, 0, stream>>>(pts4, qp, gate, pd2, pi2);
  k_knnC<<<128, 256, 0, stream>>>(pd2, pi2, ids);
  k_local<<<128, 256, 0, stream>>>(pc, W1, b1, W2, b2, lfT, lfB);
  k_genc<<<512, 512, 0, stream>>>(lfB, G1b16, g1b, G2b16, gmaxK);
  k_out<<<33280, 256, 0, stream>>>(gmaxK, g2b, lfT, ids, out);
}